// Round 1
// baseline (244.629 us; speedup 1.0000x reference)
//
#include <hip/hip_runtime.h>
#include <hip/hip_bf16.h>
#include <stdint.h>

#define N_NODES 10000
#define N_EDGES 160000
#define BUCKET 128

typedef unsigned short u16;
typedef unsigned int u32;
typedef short s16v8 __attribute__((ext_vector_type(8)));
typedef float f32v4 __attribute__((ext_vector_type(4)));

__device__ __forceinline__ float bf2f(u16 v){ return __uint_as_float(((u32)v) << 16); }
__device__ __forceinline__ u16 f2bf(float f){
    u32 u = __float_as_uint(f);
    u32 r = (u + 0x7fffu + ((u >> 16) & 1u)) >> 16;
    return (u16)r;
}

// ---------------- weights fp32->bf16 (+tconv transpose to [d][o][c]) + graph init ----------------
struct SmallPtrs { const void* p[14]; };

__device__ __constant__ const int g_seg_off[15] = {
    0, 12288, 12416, 16512, 16576, 41152, 41280,
    65856, 65984, 70080, 70144, 94720, 94848, 104064, 104076
};
// 0=straight, 1=tconv CIN=32 transpose, 2=tconv CIN=64 transpose
__device__ __constant__ const int g_seg_kind[14] = {
    1, 0, 0, 0, 2, 0, 2, 0, 0, 0, 2, 0, 0, 0
};

__global__ void k_convert_init(SmallPtrs ps, u16* __restrict__ dst,
                               float* deg, int* cur){
    int i = blockIdx.x * blockDim.x + threadIdx.x;
    if (i < 104076){
        int seg = 0, base = 0;
#pragma unroll
        for (int s = 0; s < 14; s++){
            if (i >= g_seg_off[s]){ seg = s; base = g_seg_off[s]; }
        }
        int li = i - base;
        float v = ((const float*)ps.p[seg])[li];
        int kind = g_seg_kind[seg];
        int dsto = li;
        if (kind){
            int CIN = (kind == 1) ? 32 : 64;
            int o = li / (3 * CIN);
            int rem = li - o * (3 * CIN);
            int c = rem / 3, d = rem - c * 3;
            dsto = d * 128 * CIN + o * CIN + c;     // [d][o][c]
        }
        dst[base + dsto] = f2bf(v);
    }
    if (i < N_NODES){ deg[i] = 1.0f; cur[i] = 0; }
}

// ---------------- merged: gconv32 (blocks 0..1249) || deg + bucket-scatter (1250..1874) ----------------
// LDS union: xT [8][14][40] (8960 B) overlaid with Ho [8][12][72] (13824 B) -> 13.8 KB total.
__launch_bounds__(256, 4)
__global__ void k_gconv_count(const float* __restrict__ xin, const u16* __restrict__ wg,
                              const u16* __restrict__ bg, u16* __restrict__ out,
                              const int* __restrict__ ei, const float* __restrict__ ew,
                              float* deg, int* cur, int2* __restrict__ epack){
    if (blockIdx.x >= 1250){
        int e = (blockIdx.x - 1250) * 256 + threadIdx.x;
        if (e < N_EDGES){
            int s = ei[e];
            int d = ei[N_EDGES + e];
            float wv = ew[e];
            atomicAdd(&deg[d], wv);
            int p = atomicAdd(&cur[d], 1);
            if (p < BUCKET) epack[d * BUCKET + p] = make_int2(s, __float_as_int(wv));
        }
        return;
    }
    __shared__ __attribute__((aligned(16))) u16 shbuf[6912];   // 13824 B union
    u16* xT = shbuf;    // [g][row][c] = g*560 + row*40 + c  (rows 0..13, c 0..39)
    u16* Ho = shbuf;    // [g][t][o]   = g*864 + t*72 + o    (after MFMA, overwrites xT)
    int tid = threadIdx.x;
    int n0 = blockIdx.x * 8;

    int lane = tid & 63, wave = tid >> 6;
    int col = lane & 15, quad = lane >> 4;
    int o_p = wave * 16 + col, o_q = o_p + 64;

    s16v8 Bf[3][2];
#pragma unroll
    for (int pq = 0; pq < 2; pq++){
        int o = pq ? o_q : o_p;
#pragma unroll
        for (int d = 0; d < 3; d++)
            Bf[d][pq] = *(const s16v8*)(wg + d * 4096 + o * 32 + quad * 8);
    }

    for (int i = tid; i < 8 * 40; i += 256){
        int g = i / 40, c = i % 40;
        xT[g * 560 + 0 * 40 + c] = 0; xT[g * 560 + 13 * 40 + c] = 0;
    }
    {
        int g = tid >> 5, c = tid & 31;
        const float4* p = (const float4*)(xin + ((size_t)(n0 + g) * 32 + c) * 12);
        float4 v0 = p[0], v1 = p[1], v2 = p[2];
        u16* xb = xT + g * 560 + c;
        xb[1 * 40] = f2bf(v0.x);  xb[2 * 40] = f2bf(v0.y);
        xb[3 * 40] = f2bf(v0.z);  xb[4 * 40] = f2bf(v0.w);
        xb[5 * 40] = f2bf(v1.x);  xb[6 * 40] = f2bf(v1.y);
        xb[7 * 40] = f2bf(v1.z);  xb[8 * 40] = f2bf(v1.w);
        xb[9 * 40] = f2bf(v2.x);  xb[10 * 40] = f2bf(v2.y);
        xb[11 * 40] = f2bf(v2.z); xb[12 * 40] = f2bf(v2.w);
    }
    __syncthreads();

    f32v4 aP[6], aQ[6];
#pragma unroll
    for (int mt = 0; mt < 6; mt++){ aP[mt] = (f32v4)0.f; aQ[mt] = (f32v4)0.f; }
#pragma unroll
    for (int mt = 0; mt < 6; mt++){
        int m = mt * 16 + col;
        int g = m / 12, t = m - 12 * g;
#pragma unroll
        for (int d = 0; d < 3; d++){
            s16v8 a = *(const s16v8*)&xT[g * 560 + (t + d) * 40 + quad * 8];
            aP[mt] = __builtin_amdgcn_mfma_f32_16x16x32_bf16(a, Bf[d][0], aP[mt], 0, 0, 0);
            aQ[mt] = __builtin_amdgcn_mfma_f32_16x16x32_bf16(a, Bf[d][1], aQ[mt], 0, 0, 0);
        }
    }
    __syncthreads();   // all xT reads done before Ho overwrites the union buffer
    float bP = bf2f(bg[o_p]), bQ = bf2f(bg[o_q]);
#pragma unroll
    for (int mt = 0; mt < 6; mt++){
#pragma unroll
        for (int r = 0; r < 4; r++){
            int m2 = mt * 16 + quad * 4 + r;
            int g = m2 / 12, t = m2 - 12 * g;
            float pv = aP[mt][r] + bP, qv = aQ[mt][r] + bQ;
            Ho[g * 864 + t * 72 + o_p] = f2bf(pv / (1.f + __expf(-qv)));
        }
    }
    __syncthreads();
    for (int i = tid; i < 768; i += 256){
        int g = i / 96, r = i % 96, t = r / 8, ch = r % 8;
        *(s16v8*)(out + (size_t)(n0 + g) * 768 + t * 64 + ch * 8) =
            *(const s16v8*)&Ho[g * 864 + t * 72 + ch * 8];
    }
}

// ---------------- epack normalization (once; both gathers reuse) ----------------
__global__ void k_norm(const float* __restrict__ deg, const int* __restrict__ cur,
                       int2* __restrict__ ep){
    int i = blockIdx.x * blockDim.x + threadIdx.x;
    int n = i >> 7, slot = i & 127;
    if (n >= N_NODES) return;
    int cnt = cur[n]; if (cnt > BUCKET) cnt = BUCKET;
    if (slot < cnt){
        int2 e = ep[(size_t)n * BUCKET + slot];
        float w = __int_as_float(e.y) * rsqrtf(deg[e.x]) * rsqrtf(deg[n]);
        ep[(size_t)n * BUCKET + slot].y = __float_as_int(w);
    }
}

// ---------------- slice-partitioned, edge-parallel GCN gather (pre-normalized weights) ----------------
// slice = blockIdx % 8 (XCD round-robin, per-XCD slice ~1.9 MB L2-resident).
// 8 nodes/block, 32 lanes/node: eg = edge group (4-way, adjacent-pair edges -> int4 meta),
// lane feature partition: 16B chunk (8 feats, lane-contiguous 128B span) + 8B chunk (4 feats,
// 64B span) => 3 cache-line transactions per edge-slice instead of ~9 with 24B/lane striding.
#define ACC_EDGE(W, A, B) \
    acc[0] = fmaf((W), bf2f((u16)(A)[0]), acc[0]); \
    acc[1] = fmaf((W), bf2f((u16)(A)[1]), acc[1]); \
    acc[2] = fmaf((W), bf2f((u16)(A)[2]), acc[2]); \
    acc[3] = fmaf((W), bf2f((u16)(A)[3]), acc[3]); \
    acc[4] = fmaf((W), bf2f((u16)(A)[4]), acc[4]); \
    acc[5] = fmaf((W), bf2f((u16)(A)[5]), acc[5]); \
    acc[6] = fmaf((W), bf2f((u16)(A)[6]), acc[6]); \
    acc[7] = fmaf((W), bf2f((u16)(A)[7]), acc[7]); \
    acc[8] = fmaf((W), bf2f((B).x), acc[8]); \
    acc[9] = fmaf((W), bf2f((B).y), acc[9]); \
    acc[10] = fmaf((W), bf2f((B).z), acc[10]); \
    acc[11] = fmaf((W), bf2f((B).w), acc[11]);

__launch_bounds__(256, 4)
__global__ void k_gather(const u16* __restrict__ src, const float* __restrict__ deg,
                         const int* __restrict__ cur, const int2* __restrict__ ep,
                         u16* __restrict__ z){
    int slice = blockIdx.x & 7;
    int nb = blockIdx.x >> 3;            // 0..1249
    int tid = threadIdx.x;
    int nl = tid >> 5;                   // node within block (0..7)
    int sub = tid & 31;
    int eg = sub >> 3;                   // edge group 0..3 (owns bucket slots 2g,2g+1 mod 8)
    int l8 = sub & 7;                    // feature-chunk lane 0..7
    int n = nb * 8 + nl;
    int off1 = slice * 96 + l8 * 8;      // 8 feats, 16B-aligned, lane-contiguous
    int off2 = slice * 96 + 64 + l8 * 4; // 4 feats, 8B-aligned, lane-contiguous

    float acc[12];
    if (eg == 0){
        float sw = 1.0f / deg[n];        // self-loop: dis[n]*1*dis[n]
        const u16* xr = src + (size_t)n * 768;
        s16v8 a = *(const s16v8*)(xr + off1);
        ushort4 b = *(const ushort4*)(xr + off2);
        acc[0] = sw * bf2f((u16)a[0]); acc[1] = sw * bf2f((u16)a[1]);
        acc[2] = sw * bf2f((u16)a[2]); acc[3] = sw * bf2f((u16)a[3]);
        acc[4] = sw * bf2f((u16)a[4]); acc[5] = sw * bf2f((u16)a[5]);
        acc[6] = sw * bf2f((u16)a[6]); acc[7] = sw * bf2f((u16)a[7]);
        acc[8] = sw * bf2f(b.x); acc[9] = sw * bf2f(b.y);
        acc[10] = sw * bf2f(b.z); acc[11] = sw * bf2f(b.w);
    } else {
#pragma unroll
        for (int k = 0; k < 12; k++) acc[k] = 0.f;
    }

    int e = cur[n]; if (e > BUCKET) e = BUCKET;
    const int2* eb = ep + (size_t)n * BUCKET;
    int p = eg * 2;
    // 4-edge body: two adjacent pairs (p,p+1) and (p+8,p+9); metas as two aligned int4 loads
    for (; p + 9 < e; p += 16){
        int4 m0 = *(const int4*)(eb + p);
        int4 m1 = *(const int4*)(eb + p + 8);
        const u16* q0 = src + (size_t)(u32)m0.x * 768;
        const u16* q1 = src + (size_t)(u32)m0.z * 768;
        const u16* q2 = src + (size_t)(u32)m1.x * 768;
        const u16* q3 = src + (size_t)(u32)m1.z * 768;
        s16v8 a0 = *(const s16v8*)(q0 + off1);  ushort4 b0 = *(const ushort4*)(q0 + off2);
        s16v8 a1 = *(const s16v8*)(q1 + off1);  ushort4 b1 = *(const ushort4*)(q1 + off2);
        s16v8 a2 = *(const s16v8*)(q2 + off1);  ushort4 b2 = *(const ushort4*)(q2 + off2);
        s16v8 a3 = *(const s16v8*)(q3 + off1);  ushort4 b3 = *(const ushort4*)(q3 + off2);
        float w0 = __int_as_float(m0.y), w1 = __int_as_float(m0.w);
        float w2 = __int_as_float(m1.y), w3 = __int_as_float(m1.w);
        ACC_EDGE(w0, a0, b0);
        ACC_EDGE(w1, a1, b1);
        ACC_EDGE(w2, a2, b2);
        ACC_EDGE(w3, a3, b3);
    }
    // 2-edge tail: complete pair
    for (; p + 1 < e; p += 8){
        int4 m0 = *(const int4*)(eb + p);
        const u16* q0 = src + (size_t)(u32)m0.x * 768;
        const u16* q1 = src + (size_t)(u32)m0.z * 768;
        s16v8 a0 = *(const s16v8*)(q0 + off1);  ushort4 b0 = *(const ushort4*)(q0 + off2);
        s16v8 a1 = *(const s16v8*)(q1 + off1);  ushort4 b1 = *(const ushort4*)(q1 + off2);
        float w0 = __int_as_float(m0.y), w1 = __int_as_float(m0.w);
        ACC_EDGE(w0, a0, b0);
        ACC_EDGE(w1, a1, b1);
    }
    // single tail
    if (p < e){
        int2 e0 = eb[p];
        float w0 = __int_as_float(e0.y);
        const u16* q0 = src + (size_t)(u32)e0.x * 768;
        s16v8 a0 = *(const s16v8*)(q0 + off1);  ushort4 b0 = *(const ushort4*)(q0 + off2);
        ACC_EDGE(w0, a0, b0);
    }
    // reduce edge-group partials (lanes differ in bits 3,4 — stays within each node's 32 lanes)
#pragma unroll
    for (int k = 0; k < 12; k++){
        acc[k] += __shfl_xor(acc[k], 8, 64);
        acc[k] += __shfl_xor(acc[k], 16, 64);
    }
    if (eg == 0){
        u16* zo = z + (size_t)n * 768;
        s16v8 hv;
#pragma unroll
        for (int k = 0; k < 8; k++) hv[k] = (short)f2bf(acc[k]);
        *(s16v8*)(zo + off1) = hv;
        ushort4 h2;
        h2.x = f2bf(acc[8]); h2.y = f2bf(acc[9]);
        h2.z = f2bf(acc[10]); h2.w = f2bf(acc[11]);
        *(ushort4*)(zo + off2) = h2;
    }
}

// ---------------- fused: stage z -> mix(relu) -> gconv w1 -> (MID: gconv w2 | LAST: final) ----------------
// 8 nodes/block; B-frags loaded per phase with ks-outer loop (24 VGPR live, no spills).
#define XIDX(g, row, c) (((g) * 14 + (row)) * 72 + (c))

template<bool LAST>
__launch_bounds__(256, 4)
__global__ void k_fused(const u16* __restrict__ z,      // [n][t*64+c] bf16 (pre-aggregated)
                        const u16* __restrict__ Wmix, const u16* __restrict__ bmix,
                        const u16* __restrict__ w1, const u16* __restrict__ b1,
                        const u16* __restrict__ w2, const u16* __restrict__ b2,
                        const u16* __restrict__ fw, const u16* __restrict__ fb,
                        u16* __restrict__ outMid, float* __restrict__ outFin){
    __shared__ __attribute__((aligned(16))) u16 bufX[8 * 14 * 72];
    __shared__ __attribute__((aligned(16))) u16 bufY[8 * 14 * 72];
    int tid = threadIdx.x;
    int n0 = blockIdx.x * 8;
    int lane = tid & 63, wave = tid >> 6;
    int col = lane & 15, quad = lane >> 4;
    int o_p = wave * 16 + col, o_q = o_p + 64;

    // zero time-pad rows
    for (int i = tid; i < 8 * 72; i += 256){
        int g = i / 72, c = i % 72;
        bufX[XIDX(g, 0, c)] = 0; bufX[XIDX(g, 13, c)] = 0;
        bufY[XIDX(g, 0, c)] = 0; bufY[XIDX(g, 13, c)] = 0;
    }
    // stage z -> bufX rows 1..12
    for (int i = tid; i < 768; i += 256){
        int g = i / 96, r = i % 96, t = r >> 3, ch = r & 7;
        *(s16v8*)&bufX[XIDX(g, 1 + t, ch * 8)] =
            *(const s16v8*)(z + (size_t)(n0 + g) * 768 + t * 64 + ch * 8);
    }
    __syncthreads();

    // ---- mix MFMA: y = relu(z*W + b), 6 m-tiles ----
    {
        f32v4 accm[6];
#pragma unroll
        for (int mt = 0; mt < 6; mt++) accm[mt] = (f32v4)0.f;
#pragma unroll
        for (int ks = 0; ks < 2; ks++){
            s16v8 Bm = *(const s16v8*)(Wmix + (size_t)o_p * 64 + ks * 32 + quad * 8);
#pragma unroll
            for (int mt = 0; mt < 6; mt++){
                int m = mt * 16 + col;
                int g = m / 12, t = m - 12 * g;
                s16v8 a = *(const s16v8*)&bufX[XIDX(g, 1 + t, ks * 32 + quad * 8)];
                accm[mt] = __builtin_amdgcn_mfma_f32_16x16x32_bf16(a, Bm, accm[mt], 0, 0, 0);
            }
        }
        float bm = bf2f(bmix[o_p]);
#pragma unroll
        for (int mt = 0; mt < 6; mt++){
#pragma unroll
            for (int r = 0; r < 4; r++){
                int m2 = mt * 16 + quad * 4 + r;
                int g = m2 / 12, t = m2 - 12 * g;
                bufY[XIDX(g, 1 + t, o_p)] = f2bf(fmaxf(accm[mt][r] + bm, 0.f));
            }
        }
    }
    __syncthreads();

    // ---- gated conv 1: bufY -> bufX ----
    {
        f32v4 aP[6], aQ[6];
#pragma unroll
        for (int mt = 0; mt < 6; mt++){ aP[mt] = (f32v4)0.f; aQ[mt] = (f32v4)0.f; }
#pragma unroll
        for (int ks = 0; ks < 2; ks++){
            s16v8 Bf[3][2];
#pragma unroll
            for (int pq = 0; pq < 2; pq++){
                int o = pq ? o_q : o_p;
#pragma unroll
                for (int d = 0; d < 3; d++)
                    Bf[d][pq] = *(const s16v8*)(w1 + d * 8192 + o * 64 + ks * 32 + quad * 8);
            }
#pragma unroll
            for (int mt = 0; mt < 6; mt++){
                int m = mt * 16 + col;
                int g = m / 12, t = m - 12 * g;
#pragma unroll
                for (int d = 0; d < 3; d++){
                    s16v8 a = *(const s16v8*)&bufY[XIDX(g, t + d, ks * 32 + quad * 8)];
                    aP[mt] = __builtin_amdgcn_mfma_f32_16x16x32_bf16(a, Bf[d][0], aP[mt], 0, 0, 0);
                    aQ[mt] = __builtin_amdgcn_mfma_f32_16x16x32_bf16(a, Bf[d][1], aQ[mt], 0, 0, 0);
                }
            }
        }
        float bP = bf2f(b1[o_p]), bQ = bf2f(b1[o_q]);
#pragma unroll
        for (int mt = 0; mt < 6; mt++){
#pragma unroll
            for (int r = 0; r < 4; r++){
                int m2 = mt * 16 + quad * 4 + r;
                int g = m2 / 12, t = m2 - 12 * g;
                float pv = aP[mt][r] + bP, qv = aQ[mt][r] + bQ;
                u16 hv = f2bf(pv / (1.f + __expf(-qv)));
                if (LAST) bufX[g * 1008 + o_p * 12 + t] = hv;   // H2[g][c*12+t]
                else      bufX[XIDX(g, 1 + t, o_p)] = hv;
            }
        }
    }
    __syncthreads();

    if (!LAST){
        // ---- gated conv 2: bufX -> bufY -> outMid ----
        f32v4 aP[6], aQ[6];
#pragma unroll
        for (int mt = 0; mt < 6; mt++){ aP[mt] = (f32v4)0.f; aQ[mt] = (f32v4)0.f; }
#pragma unroll
        for (int ks = 0; ks < 2; ks++){
            s16v8 Bf[3][2];
#pragma unroll
            for (int pq = 0; pq < 2; pq++){
                int o = pq ? o_q : o_p;
#pragma unroll
                for (int d = 0; d < 3; d++)
                    Bf[d][pq] = *(const s16v8*)(w2 + d * 8192 + o * 64 + ks * 32 + quad * 8);
            }
#pragma unroll
            for (int mt = 0; mt < 6; mt++){
                int m = mt * 16 + col;
                int g = m / 12, t = m - 12 * g;
#pragma unroll
                for (int d = 0; d < 3; d++){
                    s16v8 a = *(const s16v8*)&bufX[XIDX(g, t + d, ks * 32 + quad * 8)];
                    aP[mt] = __builtin_amdgcn_mfma_f32_16x16x32_bf16(a, Bf[d][0], aP[mt], 0, 0, 0);
                    aQ[mt] = __builtin_amdgcn_mfma_f32_16x16x32_bf16(a, Bf[d][1], aQ[mt], 0, 0, 0);
                }
            }
        }
        float bP = bf2f(b2[o_p]), bQ = bf2f(b2[o_q]);
#pragma unroll
        for (int mt = 0; mt < 6; mt++){
#pragma unroll
            for (int r = 0; r < 4; r++){
                int m2 = mt * 16 + quad * 4 + r;
                int g = m2 / 12, t = m2 - 12 * g;
                float pv = aP[mt][r] + bP, qv = aQ[mt][r] + bQ;
                bufY[XIDX(g, 1 + t, o_p)] = f2bf(pv / (1.f + __expf(-qv)));
            }
        }
        __syncthreads();
        for (int i = tid; i < 768; i += 256){
            int g = i / 96, r = i % 96, t = r / 8, ch = r % 8;
            *(s16v8*)(outMid + (size_t)(n0 + g) * 768 + t * 64 + ch * 8) =
                *(const s16v8*)&bufY[XIDX(g, 1 + t, ch * 8)];
        }
    } else {
        // ---- final: out[g][o] = sum_k H2[g][k]*fw[o][k] + fb[o] (wave 0; 8 nodes in rows 0..7) ----
        if (wave == 0){
            f32v4 accF = {0.f, 0.f, 0.f, 0.f};
            int g8 = col & 7;
#pragma unroll
            for (int ks = 0; ks < 24; ks++){
                s16v8 a = *(const s16v8*)&bufX[g8 * 1008 + ks * 32 + quad * 8];
                s16v8 bfr = {0, 0, 0, 0, 0, 0, 0, 0};
                if (col < 12)
                    bfr = *(const s16v8*)(fw + (size_t)col * 768 + ks * 32 + quad * 8);
                accF = __builtin_amdgcn_mfma_f32_16x16x32_bf16(a, bfr, accF, 0, 0, 0);
            }
            if (col < 12 && quad < 2){
                float bb = bf2f(fb[col]);
#pragma unroll
                for (int r = 0; r < 4; r++){
                    int g = quad * 4 + r;
                    outFin[(size_t)(n0 + g) * 12 + col] = accF[r] + bb;
                }
            }
        }
    }
}

// ---------------- launch ----------------
static inline size_t align256(size_t x){ return (x + 255) & ~(size_t)255; }

extern "C" void kernel_launch(void* const* d_in, const int* in_sizes, int n_in,
                              void* d_out, int out_size, void* d_ws, size_t ws_size,
                              hipStream_t stream){
    const float* x  = (const float*)d_in[0];
    const int* ei   = (const int*)d_in[1];
    const float* ew = (const float*)d_in[2];

    char* w = (char*)d_ws;
    u16* bufA    = (u16*)w;  w += align256((size_t)N_NODES * 768 * sizeof(u16));
    u16* bufB    = (u16*)w;  w += align256((size_t)N_NODES * 768 * sizeof(u16));
    u16* zA      = (u16*)w;  w += align256((size_t)N_NODES * 768 * sizeof(u16));
    u16* zB      = (u16*)w;  w += align256((size_t)N_NODES * 768 * sizeof(u16));
    float* deg   = (float*)w; w += align256(N_NODES * sizeof(float));
    int* cur     = (int*)w;   w += align256(N_NODES * sizeof(int));
    int2* epack  = (int2*)w;  w += align256((size_t)N_NODES * BUCKET * sizeof(int2));
    u16* cvt     = (u16*)w;   w += align256(104076 * sizeof(u16));

    u16* tc1a_w = cvt + 0;        // [d][128][32]
    u16* tc1a_b = cvt + 12288;
    u16* gc1_w  = cvt + 12416;
    u16* gc1_b  = cvt + 16512;
    u16* tc1b_w = cvt + 16576;    // [d][128][64]
    u16* tc1b_b = cvt + 41152;
    u16* tc2a_w = cvt + 41280;    // [d][128][64]
    u16* tc2a_b = cvt + 65856;
    u16* gc2_w  = cvt + 65984;
    u16* gc2_b  = cvt + 70080;
    u16* tc2b_w = cvt + 70144;    // [d][128][64]
    u16* tc2b_b = cvt + 94720;
    u16* fin_w  = cvt + 94848;
    u16* fin_b  = cvt + 104064;

    SmallPtrs ps;
    ps.p[0]  = d_in[3];  ps.p[1]  = d_in[4];
    ps.p[2]  = d_in[5];  ps.p[3]  = d_in[6];
    ps.p[4]  = d_in[7];  ps.p[5]  = d_in[8];
    ps.p[6]  = d_in[9];  ps.p[7]  = d_in[10];
    ps.p[8]  = d_in[11]; ps.p[9]  = d_in[12];
    ps.p[10] = d_in[13]; ps.p[11] = d_in[14];
    ps.p[12] = d_in[15]; ps.p[13] = d_in[16];

    k_convert_init<<<(104076 + 255) / 256, 256, 0, stream>>>(ps, cvt, deg, cur);
    k_gconv_count<<<1250 + 625, 256, 0, stream>>>(x, tc1a_w, tc1a_b, bufA, ei, ew, deg, cur, epack);
    k_norm<<<(N_NODES * BUCKET) / 256, 256, 0, stream>>>(deg, cur, epack);

    k_gather<<<1250 * 8, 256, 0, stream>>>(bufA, deg, cur, epack, zA);
    k_fused<false><<<1250, 256, 0, stream>>>(zA, gc1_w, gc1_b, tc1b_w, tc1b_b,
                                             tc2a_w, tc2a_b, nullptr, nullptr,
                                             bufB, nullptr);
    k_gather<<<1250 * 8, 256, 0, stream>>>(bufB, deg, cur, epack, zB);
    k_fused<true><<<1250, 256, 0, stream>>>(zB, gc2_w, gc2_b, tc2b_w, tc2b_b,
                                            nullptr, nullptr, fin_w, fin_b,
                                            nullptr, (float*)d_out);
}

// Round 2
// 240.202 us; speedup vs baseline: 1.0184x; 1.0184x over previous
//
#include <hip/hip_runtime.h>
#include <hip/hip_bf16.h>
#include <stdint.h>

#define N_NODES 10000
#define N_EDGES 160000
#define BUCKET 128
#define UNROLL_SLOTS 24   // slots [0,24) processed branchlessly; k_norm zero-pads [cnt,24)

typedef unsigned short u16;
typedef unsigned int u32;
typedef short s16v8 __attribute__((ext_vector_type(8)));
typedef float f32v4 __attribute__((ext_vector_type(4)));
typedef float f32v2 __attribute__((ext_vector_type(2)));
typedef unsigned int u32v4 __attribute__((ext_vector_type(4)));
typedef unsigned int u32v2 __attribute__((ext_vector_type(2)));

__device__ __forceinline__ float bf2f(u16 v){ return __uint_as_float(((u32)v) << 16); }
__device__ __forceinline__ u16 f2bf(float f){
    u32 u = __float_as_uint(f);
    u32 r = (u + 0x7fffu + ((u >> 16) & 1u)) >> 16;
    return (u16)r;
}
// unpack u32 holding 2 bf16 -> float2 (lo, hi)
__device__ __forceinline__ f32v2 up2(u32 v){
    f32v2 r;
    r.x = __uint_as_float(v << 16);
    r.y = __uint_as_float(v & 0xffff0000u);
    return r;
}
__device__ __forceinline__ u32 pk2(float lo, float hi){
    return (u32)f2bf(lo) | ((u32)f2bf(hi) << 16);
}

// ---------------- weights fp32->bf16 (+tconv transpose to [d][o][c]) + graph init ----------------
struct SmallPtrs { const void* p[14]; };

__device__ __constant__ const int g_seg_off[15] = {
    0, 12288, 12416, 16512, 16576, 41152, 41280,
    65856, 65984, 70080, 70144, 94720, 94848, 104064, 104076
};
// 0=straight, 1=tconv CIN=32 transpose, 2=tconv CIN=64 transpose
__device__ __constant__ const int g_seg_kind[14] = {
    1, 0, 0, 0, 2, 0, 2, 0, 0, 0, 2, 0, 0, 0
};

__global__ void k_convert_init(SmallPtrs ps, u16* __restrict__ dst,
                               float* deg, int* cur){
    int i = blockIdx.x * blockDim.x + threadIdx.x;
    if (i < 104076){
        int seg = 0, base = 0;
#pragma unroll
        for (int s = 0; s < 14; s++){
            if (i >= g_seg_off[s]){ seg = s; base = g_seg_off[s]; }
        }
        int li = i - base;
        float v = ((const float*)ps.p[seg])[li];
        int kind = g_seg_kind[seg];
        int dsto = li;
        if (kind){
            int CIN = (kind == 1) ? 32 : 64;
            int o = li / (3 * CIN);
            int rem = li - o * (3 * CIN);
            int c = rem / 3, d = rem - c * 3;
            dsto = d * 128 * CIN + o * CIN + c;     // [d][o][c]
        }
        dst[base + dsto] = f2bf(v);
    }
    if (i < N_NODES){ deg[i] = 1.0f; cur[i] = 0; }
}

// ---------------- merged: gconv32 (blocks 0..1249) || deg + bucket-scatter (1250..1874) ----------------
// LDS union: xT [8][14][40] (8960 B) overlaid with Ho [8][12][72] (13824 B) -> 13.8 KB total.
__launch_bounds__(256, 4)
__global__ void k_gconv_count(const float* __restrict__ xin, const u16* __restrict__ wg,
                              const u16* __restrict__ bg, u16* __restrict__ out,
                              const int* __restrict__ ei, const float* __restrict__ ew,
                              float* deg, int* cur, int2* __restrict__ epack){
    if (blockIdx.x >= 1250){
        int e = (blockIdx.x - 1250) * 256 + threadIdx.x;
        if (e < N_EDGES){
            int s = ei[e];
            int d = ei[N_EDGES + e];
            float wv = ew[e];
            atomicAdd(&deg[d], wv);
            int p = atomicAdd(&cur[d], 1);
            if (p < BUCKET) epack[d * BUCKET + p] = make_int2(s, __float_as_int(wv));
        }
        return;
    }
    __shared__ __attribute__((aligned(16))) u16 shbuf[6912];   // 13824 B union
    u16* xT = shbuf;    // [g][row][c] = g*560 + row*40 + c  (rows 0..13, c 0..39)
    u16* Ho = shbuf;    // [g][t][o]   = g*864 + t*72 + o    (after MFMA, overwrites xT)
    int tid = threadIdx.x;
    int n0 = blockIdx.x * 8;

    int lane = tid & 63, wave = tid >> 6;
    int col = lane & 15, quad = lane >> 4;
    int o_p = wave * 16 + col, o_q = o_p + 64;

    s16v8 Bf[3][2];
#pragma unroll
    for (int pq = 0; pq < 2; pq++){
        int o = pq ? o_q : o_p;
#pragma unroll
        for (int d = 0; d < 3; d++)
            Bf[d][pq] = *(const s16v8*)(wg + d * 4096 + o * 32 + quad * 8);
    }

    for (int i = tid; i < 8 * 40; i += 256){
        int g = i / 40, c = i % 40;
        xT[g * 560 + 0 * 40 + c] = 0; xT[g * 560 + 13 * 40 + c] = 0;
    }
    {
        int g = tid >> 5, c = tid & 31;
        const float4* p = (const float4*)(xin + ((size_t)(n0 + g) * 32 + c) * 12);
        float4 v0 = p[0], v1 = p[1], v2 = p[2];
        u16* xb = xT + g * 560 + c;
        xb[1 * 40] = f2bf(v0.x);  xb[2 * 40] = f2bf(v0.y);
        xb[3 * 40] = f2bf(v0.z);  xb[4 * 40] = f2bf(v0.w);
        xb[5 * 40] = f2bf(v1.x);  xb[6 * 40] = f2bf(v1.y);
        xb[7 * 40] = f2bf(v1.z);  xb[8 * 40] = f2bf(v1.w);
        xb[9 * 40] = f2bf(v2.x);  xb[10 * 40] = f2bf(v2.y);
        xb[11 * 40] = f2bf(v2.z); xb[12 * 40] = f2bf(v2.w);
    }
    __syncthreads();

    f32v4 aP[6], aQ[6];
#pragma unroll
    for (int mt = 0; mt < 6; mt++){ aP[mt] = (f32v4)0.f; aQ[mt] = (f32v4)0.f; }
#pragma unroll
    for (int mt = 0; mt < 6; mt++){
        int m = mt * 16 + col;
        int g = m / 12, t = m - 12 * g;
#pragma unroll
        for (int d = 0; d < 3; d++){
            s16v8 a = *(const s16v8*)&xT[g * 560 + (t + d) * 40 + quad * 8];
            aP[mt] = __builtin_amdgcn_mfma_f32_16x16x32_bf16(a, Bf[d][0], aP[mt], 0, 0, 0);
            aQ[mt] = __builtin_amdgcn_mfma_f32_16x16x32_bf16(a, Bf[d][1], aQ[mt], 0, 0, 0);
        }
    }
    __syncthreads();   // all xT reads done before Ho overwrites the union buffer
    float bP = bf2f(bg[o_p]), bQ = bf2f(bg[o_q]);
#pragma unroll
    for (int mt = 0; mt < 6; mt++){
#pragma unroll
        for (int r = 0; r < 4; r++){
            int m2 = mt * 16 + quad * 4 + r;
            int g = m2 / 12, t = m2 - 12 * g;
            float pv = aP[mt][r] + bP, qv = aQ[mt][r] + bQ;
            Ho[g * 864 + t * 72 + o_p] = f2bf(pv / (1.f + __expf(-qv)));
        }
    }
    __syncthreads();
    for (int i = tid; i < 768; i += 256){
        int g = i / 96, r = i % 96, t = r / 8, ch = r % 8;
        *(s16v8*)(out + (size_t)(n0 + g) * 768 + t * 64 + ch * 8) =
            *(const s16v8*)&Ho[g * 864 + t * 72 + ch * 8];
    }
}

// ---------------- epack normalization + zero-pad slots [cnt, UNROLL_SLOTS) ----------------
__global__ void k_norm(const float* __restrict__ deg, const int* __restrict__ cur,
                       int2* __restrict__ ep){
    int i = blockIdx.x * blockDim.x + threadIdx.x;
    int n = i >> 7, slot = i & 127;
    if (n >= N_NODES) return;
    int cnt = cur[n]; if (cnt > BUCKET) cnt = BUCKET;
    if (slot < cnt){
        int2 e = ep[(size_t)n * BUCKET + slot];
        float w = __int_as_float(e.y) * rsqrtf(deg[e.x]) * rsqrtf(deg[n]);
        ep[(size_t)n * BUCKET + slot].y = __float_as_int(w);
    } else if (slot < UNROLL_SLOTS){
        // pad: src=node 0 (row stays L1-hot), weight=0 -> contributes exact 0
        ep[(size_t)n * BUCKET + slot] = make_int2(0, 0);
    }
}

// ---------------- slice-partitioned, edge-parallel GCN gather (pre-normalized weights) ----------------
// slice = blockIdx % 8 (XCD round-robin, per-XCD slice ~1.9 MB L2-resident).
// 8 nodes/block, 32 lanes/node: eg = edge group 0..3, l8 = feature lane 0..7 (12 feats/lane).
// Branchless main path: slots [0,24) processed unconditionally (zero-padded by k_norm) ->
// all meta+feature loads issue immediately, no cur[n]-dependent control flow, max MLP.
// Accumulation in packed float2 -> v_pk_fma_f32 halves FMA instruction count.
#define GATHER2(P) { \
    int4 m = *(const int4*)(eb + (P)); \
    const u16* q0 = src + (size_t)(u32)m.x * 768; \
    const u16* q1 = src + (size_t)(u32)m.z * 768; \
    u32v4 a0 = *(const u32v4*)(q0 + off1); u32v2 b0 = *(const u32v2*)(q0 + off2); \
    u32v4 a1 = *(const u32v4*)(q1 + off1); u32v2 b1 = *(const u32v2*)(q1 + off2); \
    f32v2 w0; w0.x = __int_as_float(m.y); w0.y = w0.x; \
    f32v2 w1; w1.x = __int_as_float(m.w); w1.y = w1.x; \
    acc[0] += w0 * up2(a0.x); acc[1] += w0 * up2(a0.y); \
    acc[2] += w0 * up2(a0.z); acc[3] += w0 * up2(a0.w); \
    acc[4] += w0 * up2(b0.x); acc[5] += w0 * up2(b0.y); \
    acc[0] += w1 * up2(a1.x); acc[1] += w1 * up2(a1.y); \
    acc[2] += w1 * up2(a1.z); acc[3] += w1 * up2(a1.w); \
    acc[4] += w1 * up2(b1.x); acc[5] += w1 * up2(b1.y); }

#define GATHER1(P) { \
    int2 e0 = eb[(P)]; \
    const u16* q0 = src + (size_t)(u32)e0.x * 768; \
    u32v4 a0 = *(const u32v4*)(q0 + off1); u32v2 b0 = *(const u32v2*)(q0 + off2); \
    f32v2 w0; w0.x = __int_as_float(e0.y); w0.y = w0.x; \
    acc[0] += w0 * up2(a0.x); acc[1] += w0 * up2(a0.y); \
    acc[2] += w0 * up2(a0.z); acc[3] += w0 * up2(a0.w); \
    acc[4] += w0 * up2(b0.x); acc[5] += w0 * up2(b0.y); }

__launch_bounds__(256, 4)
__global__ void k_gather(const u16* __restrict__ src, const float* __restrict__ deg,
                         const int* __restrict__ cur, const int2* __restrict__ ep,
                         u16* __restrict__ z){
    int slice = blockIdx.x & 7;
    int nb = blockIdx.x >> 3;            // 0..1249
    int tid = threadIdx.x;
    int nl = tid >> 5;                   // node within block (0..7)
    int sub = tid & 31;
    int eg = sub >> 3;                   // edge group 0..3 (owns bucket slots 2g,2g+1 mod 8)
    int l8 = sub & 7;                    // feature-chunk lane 0..7
    int n = nb * 8 + nl;
    int off1 = slice * 96 + l8 * 8;      // 8 feats, 16B-aligned, lane-contiguous
    int off2 = slice * 96 + 64 + l8 * 4; // 4 feats, 8B-aligned, lane-contiguous

    f32v2 acc[6];
    if (eg == 0){
        float sw = 1.0f / deg[n];        // self-loop: dis[n]*1*dis[n]
        f32v2 swv; swv.x = sw; swv.y = sw;
        const u16* xr = src + (size_t)n * 768;
        u32v4 sa = *(const u32v4*)(xr + off1);
        u32v2 sb = *(const u32v2*)(xr + off2);
        acc[0] = swv * up2(sa.x); acc[1] = swv * up2(sa.y);
        acc[2] = swv * up2(sa.z); acc[3] = swv * up2(sa.w);
        acc[4] = swv * up2(sb.x); acc[5] = swv * up2(sb.y);
    } else {
#pragma unroll
        for (int k = 0; k < 6; k++) acc[k] = (f32v2)0.f;
    }

    const int2* eb = ep + (size_t)n * BUCKET;
    // branchless main path: slots [0,24), zero-padded beyond cnt
    GATHER2(eg * 2);
    GATHER2(eg * 2 + 8);
    GATHER2(eg * 2 + 16);

    // rare tail (P(deg>24) ~ 2%): pair loop over slots [24, cnt)
    int e = cur[n]; if (e > BUCKET) e = BUCKET;
    if (e > UNROLL_SLOTS){
        int p = UNROLL_SLOTS + eg * 2;
        for (; p + 1 < e; p += 8) GATHER2(p);
        if (p < e) GATHER1(p);
    }

    // reduce edge-group partials (lanes differ in bits 3,4 — stays within each node's 32 lanes)
    float r[12];
#pragma unroll
    for (int j = 0; j < 6; j++){ r[2 * j] = acc[j].x; r[2 * j + 1] = acc[j].y; }
#pragma unroll
    for (int k = 0; k < 12; k++){
        r[k] += __shfl_xor(r[k], 8, 64);
        r[k] += __shfl_xor(r[k], 16, 64);
    }
    if (eg == 0){
        u16* zo = z + (size_t)n * 768;
        u32v4 ha; ha.x = pk2(r[0], r[1]); ha.y = pk2(r[2], r[3]);
        ha.z = pk2(r[4], r[5]); ha.w = pk2(r[6], r[7]);
        u32v2 hb; hb.x = pk2(r[8], r[9]); hb.y = pk2(r[10], r[11]);
        *(u32v4*)(zo + off1) = ha;
        *(u32v2*)(zo + off2) = hb;
    }
}

// ---------------- fused: stage z -> mix(relu) -> gconv w1 -> (MID: gconv w2 | LAST: final) ----------------
// 8 nodes/block; B-frags loaded per phase with ks-outer loop (24 VGPR live, no spills).
#define XIDX(g, row, c) (((g) * 14 + (row)) * 72 + (c))

template<bool LAST>
__launch_bounds__(256, 4)
__global__ void k_fused(const u16* __restrict__ z,      // [n][t*64+c] bf16 (pre-aggregated)
                        const u16* __restrict__ Wmix, const u16* __restrict__ bmix,
                        const u16* __restrict__ w1, const u16* __restrict__ b1,
                        const u16* __restrict__ w2, const u16* __restrict__ b2,
                        const u16* __restrict__ fw, const u16* __restrict__ fb,
                        u16* __restrict__ outMid, float* __restrict__ outFin){
    __shared__ __attribute__((aligned(16))) u16 bufX[8 * 14 * 72];
    __shared__ __attribute__((aligned(16))) u16 bufY[8 * 14 * 72];
    int tid = threadIdx.x;
    int n0 = blockIdx.x * 8;
    int lane = tid & 63, wave = tid >> 6;
    int col = lane & 15, quad = lane >> 4;
    int o_p = wave * 16 + col, o_q = o_p + 64;

    // zero time-pad rows
    for (int i = tid; i < 8 * 72; i += 256){
        int g = i / 72, c = i % 72;
        bufX[XIDX(g, 0, c)] = 0; bufX[XIDX(g, 13, c)] = 0;
        bufY[XIDX(g, 0, c)] = 0; bufY[XIDX(g, 13, c)] = 0;
    }
    // stage z -> bufX rows 1..12
    for (int i = tid; i < 768; i += 256){
        int g = i / 96, r = i % 96, t = r >> 3, ch = r & 7;
        *(s16v8*)&bufX[XIDX(g, 1 + t, ch * 8)] =
            *(const s16v8*)(z + (size_t)(n0 + g) * 768 + t * 64 + ch * 8);
    }
    __syncthreads();

    // ---- mix MFMA: y = relu(z*W + b), 6 m-tiles ----
    {
        f32v4 accm[6];
#pragma unroll
        for (int mt = 0; mt < 6; mt++) accm[mt] = (f32v4)0.f;
#pragma unroll
        for (int ks = 0; ks < 2; ks++){
            s16v8 Bm = *(const s16v8*)(Wmix + (size_t)o_p * 64 + ks * 32 + quad * 8);
#pragma unroll
            for (int mt = 0; mt < 6; mt++){
                int m = mt * 16 + col;
                int g = m / 12, t = m - 12 * g;
                s16v8 a = *(const s16v8*)&bufX[XIDX(g, 1 + t, ks * 32 + quad * 8)];
                accm[mt] = __builtin_amdgcn_mfma_f32_16x16x32_bf16(a, Bm, accm[mt], 0, 0, 0);
            }
        }
        float bm = bf2f(bmix[o_p]);
#pragma unroll
        for (int mt = 0; mt < 6; mt++){
#pragma unroll
            for (int r = 0; r < 4; r++){
                int m2 = mt * 16 + quad * 4 + r;
                int g = m2 / 12, t = m2 - 12 * g;
                bufY[XIDX(g, 1 + t, o_p)] = f2bf(fmaxf(accm[mt][r] + bm, 0.f));
            }
        }
    }
    __syncthreads();

    // ---- gated conv 1: bufY -> bufX ----
    {
        f32v4 aP[6], aQ[6];
#pragma unroll
        for (int mt = 0; mt < 6; mt++){ aP[mt] = (f32v4)0.f; aQ[mt] = (f32v4)0.f; }
#pragma unroll
        for (int ks = 0; ks < 2; ks++){
            s16v8 Bf[3][2];
#pragma unroll
            for (int pq = 0; pq < 2; pq++){
                int o = pq ? o_q : o_p;
#pragma unroll
                for (int d = 0; d < 3; d++)
                    Bf[d][pq] = *(const s16v8*)(w1 + d * 8192 + o * 64 + ks * 32 + quad * 8);
            }
#pragma unroll
            for (int mt = 0; mt < 6; mt++){
                int m = mt * 16 + col;
                int g = m / 12, t = m - 12 * g;
#pragma unroll
                for (int d = 0; d < 3; d++){
                    s16v8 a = *(const s16v8*)&bufY[XIDX(g, t + d, ks * 32 + quad * 8)];
                    aP[mt] = __builtin_amdgcn_mfma_f32_16x16x32_bf16(a, Bf[d][0], aP[mt], 0, 0, 0);
                    aQ[mt] = __builtin_amdgcn_mfma_f32_16x16x32_bf16(a, Bf[d][1], aQ[mt], 0, 0, 0);
                }
            }
        }
        float bP = bf2f(b1[o_p]), bQ = bf2f(b1[o_q]);
#pragma unroll
        for (int mt = 0; mt < 6; mt++){
#pragma unroll
            for (int r = 0; r < 4; r++){
                int m2 = mt * 16 + quad * 4 + r;
                int g = m2 / 12, t = m2 - 12 * g;
                float pv = aP[mt][r] + bP, qv = aQ[mt][r] + bQ;
                u16 hv = f2bf(pv / (1.f + __expf(-qv)));
                if (LAST) bufX[g * 1008 + o_p * 12 + t] = hv;   // H2[g][c*12+t]
                else      bufX[XIDX(g, 1 + t, o_p)] = hv;
            }
        }
    }
    __syncthreads();

    if (!LAST){
        // ---- gated conv 2: bufX -> bufY -> outMid ----
        f32v4 aP[6], aQ[6];
#pragma unroll
        for (int mt = 0; mt < 6; mt++){ aP[mt] = (f32v4)0.f; aQ[mt] = (f32v4)0.f; }
#pragma unroll
        for (int ks = 0; ks < 2; ks++){
            s16v8 Bf[3][2];
#pragma unroll
            for (int pq = 0; pq < 2; pq++){
                int o = pq ? o_q : o_p;
#pragma unroll
                for (int d = 0; d < 3; d++)
                    Bf[d][pq] = *(const s16v8*)(w2 + d * 8192 + o * 64 + ks * 32 + quad * 8);
            }
#pragma unroll
            for (int mt = 0; mt < 6; mt++){
                int m = mt * 16 + col;
                int g = m / 12, t = m - 12 * g;
#pragma unroll
                for (int d = 0; d < 3; d++){
                    s16v8 a = *(const s16v8*)&bufX[XIDX(g, t + d, ks * 32 + quad * 8)];
                    aP[mt] = __builtin_amdgcn_mfma_f32_16x16x32_bf16(a, Bf[d][0], aP[mt], 0, 0, 0);
                    aQ[mt] = __builtin_amdgcn_mfma_f32_16x16x32_bf16(a, Bf[d][1], aQ[mt], 0, 0, 0);
                }
            }
        }
        float bP = bf2f(b2[o_p]), bQ = bf2f(b2[o_q]);
#pragma unroll
        for (int mt = 0; mt < 6; mt++){
#pragma unroll
            for (int r = 0; r < 4; r++){
                int m2 = mt * 16 + quad * 4 + r;
                int g = m2 / 12, t = m2 - 12 * g;
                float pv = aP[mt][r] + bP, qv = aQ[mt][r] + bQ;
                bufY[XIDX(g, 1 + t, o_p)] = f2bf(pv / (1.f + __expf(-qv)));
            }
        }
        __syncthreads();
        for (int i = tid; i < 768; i += 256){
            int g = i / 96, r = i % 96, t = r / 8, ch = r % 8;
            *(s16v8*)(outMid + (size_t)(n0 + g) * 768 + t * 64 + ch * 8) =
                *(const s16v8*)&bufY[XIDX(g, 1 + t, ch * 8)];
        }
    } else {
        // ---- final: out[g][o] = sum_k H2[g][k]*fw[o][k] + fb[o] (wave 0; 8 nodes in rows 0..7) ----
        if (wave == 0){
            f32v4 accF = {0.f, 0.f, 0.f, 0.f};
            int g8 = col & 7;
#pragma unroll
            for (int ks = 0; ks < 24; ks++){
                s16v8 a = *(const s16v8*)&bufX[g8 * 1008 + ks * 32 + quad * 8];
                s16v8 bfr = {0, 0, 0, 0, 0, 0, 0, 0};
                if (col < 12)
                    bfr = *(const s16v8*)(fw + (size_t)col * 768 + ks * 32 + quad * 8);
                accF = __builtin_amdgcn_mfma_f32_16x16x32_bf16(a, bfr, accF, 0, 0, 0);
            }
            if (col < 12 && quad < 2){
                float bb = bf2f(fb[col]);
#pragma unroll
                for (int r = 0; r < 4; r++){
                    int g = quad * 4 + r;
                    outFin[(size_t)(n0 + g) * 12 + col] = accF[r] + bb;
                }
            }
        }
    }
}

// ---------------- launch ----------------
static inline size_t align256(size_t x){ return (x + 255) & ~(size_t)255; }

extern "C" void kernel_launch(void* const* d_in, const int* in_sizes, int n_in,
                              void* d_out, int out_size, void* d_ws, size_t ws_size,
                              hipStream_t stream){
    const float* x  = (const float*)d_in[0];
    const int* ei   = (const int*)d_in[1];
    const float* ew = (const float*)d_in[2];

    char* w = (char*)d_ws;
    u16* bufA    = (u16*)w;  w += align256((size_t)N_NODES * 768 * sizeof(u16));
    u16* bufB    = (u16*)w;  w += align256((size_t)N_NODES * 768 * sizeof(u16));
    u16* zA      = (u16*)w;  w += align256((size_t)N_NODES * 768 * sizeof(u16));
    u16* zB      = (u16*)w;  w += align256((size_t)N_NODES * 768 * sizeof(u16));
    float* deg   = (float*)w; w += align256(N_NODES * sizeof(float));
    int* cur     = (int*)w;   w += align256(N_NODES * sizeof(int));
    int2* epack  = (int2*)w;  w += align256((size_t)N_NODES * BUCKET * sizeof(int2));
    u16* cvt     = (u16*)w;   w += align256(104076 * sizeof(u16));

    u16* tc1a_w = cvt + 0;        // [d][128][32]
    u16* tc1a_b = cvt + 12288;
    u16* gc1_w  = cvt + 12416;
    u16* gc1_b  = cvt + 16512;
    u16* tc1b_w = cvt + 16576;    // [d][128][64]
    u16* tc1b_b = cvt + 41152;
    u16* tc2a_w = cvt + 41280;    // [d][128][64]
    u16* tc2a_b = cvt + 65856;
    u16* gc2_w  = cvt + 65984;
    u16* gc2_b  = cvt + 70080;
    u16* tc2b_w = cvt + 70144;    // [d][128][64]
    u16* tc2b_b = cvt + 94720;
    u16* fin_w  = cvt + 94848;
    u16* fin_b  = cvt + 104064;

    SmallPtrs ps;
    ps.p[0]  = d_in[3];  ps.p[1]  = d_in[4];
    ps.p[2]  = d_in[5];  ps.p[3]  = d_in[6];
    ps.p[4]  = d_in[7];  ps.p[5]  = d_in[8];
    ps.p[6]  = d_in[9];  ps.p[7]  = d_in[10];
    ps.p[8]  = d_in[11]; ps.p[9]  = d_in[12];
    ps.p[10] = d_in[13]; ps.p[11] = d_in[14];
    ps.p[12] = d_in[15]; ps.p[13] = d_in[16];

    k_convert_init<<<(104076 + 255) / 256, 256, 0, stream>>>(ps, cvt, deg, cur);
    k_gconv_count<<<1250 + 625, 256, 0, stream>>>(x, tc1a_w, tc1a_b, bufA, ei, ew, deg, cur, epack);
    k_norm<<<(N_NODES * BUCKET) / 256, 256, 0, stream>>>(deg, cur, epack);

    k_gather<<<1250 * 8, 256, 0, stream>>>(bufA, deg, cur, epack, zA);
    k_fused<false><<<1250, 256, 0, stream>>>(zA, gc1_w, gc1_b, tc1b_w, tc1b_b,
                                             tc2a_w, tc2a_b, nullptr, nullptr,
                                             bufB, nullptr);
    k_gather<<<1250 * 8, 256, 0, stream>>>(bufB, deg, cur, epack, zB);
    k_fused<true><<<1250, 256, 0, stream>>>(zB, gc2_w, gc2_b, tc2b_w, tc2b_b,
                                            nullptr, nullptr, fin_w, fin_b,
                                            nullptr, (float*)d_out);
}

// Round 3
// 226.731 us; speedup vs baseline: 1.0789x; 1.0594x over previous
//
#include <hip/hip_runtime.h>
#include <hip/hip_bf16.h>
#include <stdint.h>

#define N_NODES 10000
#define N_EDGES 160000
#define BUCKET 128
#define UNROLL_SLOTS 24   // slots [0,24) processed branchlessly; k_norm zero-pads [cnt,24)

typedef unsigned short u16;
typedef unsigned int u32;
typedef short s16v8 __attribute__((ext_vector_type(8)));
typedef float f32v4 __attribute__((ext_vector_type(4)));
typedef float f32v2 __attribute__((ext_vector_type(2)));
typedef unsigned int u32v4 __attribute__((ext_vector_type(4)));
typedef unsigned int u32v2 __attribute__((ext_vector_type(2)));

__device__ __forceinline__ float bf2f(u16 v){ return __uint_as_float(((u32)v) << 16); }
__device__ __forceinline__ u16 f2bf(float f){
    u32 u = __float_as_uint(f);
    u32 r = (u + 0x7fffu + ((u >> 16) & 1u)) >> 16;
    return (u16)r;
}
// unpack u32 holding 2 bf16 -> float2 (lo, hi)
__device__ __forceinline__ f32v2 up2(u32 v){
    f32v2 r;
    r.x = __uint_as_float(v << 16);
    r.y = __uint_as_float(v & 0xffff0000u);
    return r;
}
__device__ __forceinline__ u32 pk2(float lo, float hi){
    return (u32)f2bf(lo) | ((u32)f2bf(hi) << 16);
}

// ---------------- weights fp32->bf16 (+tconv transpose to [d][o][c]) + graph init ----------------
struct SmallPtrs { const void* p[14]; };

__device__ __constant__ const int g_seg_off[15] = {
    0, 12288, 12416, 16512, 16576, 41152, 41280,
    65856, 65984, 70080, 70144, 94720, 94848, 104064, 104076
};
// 0=straight, 1=tconv CIN=32 transpose, 2=tconv CIN=64 transpose
__device__ __constant__ const int g_seg_kind[14] = {
    1, 0, 0, 0, 2, 0, 2, 0, 0, 0, 2, 0, 0, 0
};

__global__ void k_convert_init(SmallPtrs ps, u16* __restrict__ dst,
                               float* deg, int* cur){
    int i = blockIdx.x * blockDim.x + threadIdx.x;
    if (i < 104076){
        int seg = 0, base = 0;
#pragma unroll
        for (int s = 0; s < 14; s++){
            if (i >= g_seg_off[s]){ seg = s; base = g_seg_off[s]; }
        }
        int li = i - base;
        float v = ((const float*)ps.p[seg])[li];
        int kind = g_seg_kind[seg];
        int dsto = li;
        if (kind){
            int CIN = (kind == 1) ? 32 : 64;
            int o = li / (3 * CIN);
            int rem = li - o * (3 * CIN);
            int c = rem / 3, d = rem - c * 3;
            dsto = d * 128 * CIN + o * CIN + c;     // [d][o][c]
        }
        dst[base + dsto] = f2bf(v);
    }
    if (i < N_NODES){ deg[i] = 1.0f; cur[i] = 0; }
}

// ---------------- merged: gconv32 (blocks 0..1249) || deg + bucket-scatter (1250..1874) ----------------
// LDS union: xT [8][14][40] (8960 B) overlaid with Ho [8][12][72] (13824 B) -> 13.8 KB total.
__launch_bounds__(256, 4)
__global__ void k_gconv_count(const float* __restrict__ xin, const u16* __restrict__ wg,
                              const u16* __restrict__ bg, u16* __restrict__ out,
                              const int* __restrict__ ei, const float* __restrict__ ew,
                              float* deg, int* cur, int2* __restrict__ epack){
    if (blockIdx.x >= 1250){
        int e = (blockIdx.x - 1250) * 256 + threadIdx.x;
        if (e < N_EDGES){
            int s = ei[e];
            int d = ei[N_EDGES + e];
            float wv = ew[e];
            atomicAdd(&deg[d], wv);
            int p = atomicAdd(&cur[d], 1);
            if (p < BUCKET) epack[d * BUCKET + p] = make_int2(s, __float_as_int(wv));
        }
        return;
    }
    __shared__ __attribute__((aligned(16))) u16 shbuf[6912];   // 13824 B union
    u16* xT = shbuf;    // [g][row][c] = g*560 + row*40 + c  (rows 0..13, c 0..39)
    u16* Ho = shbuf;    // [g][t][o]   = g*864 + t*72 + o    (after MFMA, overwrites xT)
    int tid = threadIdx.x;
    int n0 = blockIdx.x * 8;

    int lane = tid & 63, wave = tid >> 6;
    int col = lane & 15, quad = lane >> 4;
    int o_p = wave * 16 + col, o_q = o_p + 64;

    s16v8 Bf[3][2];
#pragma unroll
    for (int pq = 0; pq < 2; pq++){
        int o = pq ? o_q : o_p;
#pragma unroll
        for (int d = 0; d < 3; d++)
            Bf[d][pq] = *(const s16v8*)(wg + d * 4096 + o * 32 + quad * 8);
    }

    for (int i = tid; i < 8 * 40; i += 256){
        int g = i / 40, c = i % 40;
        xT[g * 560 + 0 * 40 + c] = 0; xT[g * 560 + 13 * 40 + c] = 0;
    }
    {
        int g = tid >> 5, c = tid & 31;
        const float4* p = (const float4*)(xin + ((size_t)(n0 + g) * 32 + c) * 12);
        float4 v0 = p[0], v1 = p[1], v2 = p[2];
        u16* xb = xT + g * 560 + c;
        xb[1 * 40] = f2bf(v0.x);  xb[2 * 40] = f2bf(v0.y);
        xb[3 * 40] = f2bf(v0.z);  xb[4 * 40] = f2bf(v0.w);
        xb[5 * 40] = f2bf(v1.x);  xb[6 * 40] = f2bf(v1.y);
        xb[7 * 40] = f2bf(v1.z);  xb[8 * 40] = f2bf(v1.w);
        xb[9 * 40] = f2bf(v2.x);  xb[10 * 40] = f2bf(v2.y);
        xb[11 * 40] = f2bf(v2.z); xb[12 * 40] = f2bf(v2.w);
    }
    __syncthreads();

    f32v4 aP[6], aQ[6];
#pragma unroll
    for (int mt = 0; mt < 6; mt++){ aP[mt] = (f32v4)0.f; aQ[mt] = (f32v4)0.f; }
#pragma unroll
    for (int mt = 0; mt < 6; mt++){
        int m = mt * 16 + col;
        int g = m / 12, t = m - 12 * g;
#pragma unroll
        for (int d = 0; d < 3; d++){
            s16v8 a = *(const s16v8*)&xT[g * 560 + (t + d) * 40 + quad * 8];
            aP[mt] = __builtin_amdgcn_mfma_f32_16x16x32_bf16(a, Bf[d][0], aP[mt], 0, 0, 0);
            aQ[mt] = __builtin_amdgcn_mfma_f32_16x16x32_bf16(a, Bf[d][1], aQ[mt], 0, 0, 0);
        }
    }
    __syncthreads();   // all xT reads done before Ho overwrites the union buffer
    float bP = bf2f(bg[o_p]), bQ = bf2f(bg[o_q]);
#pragma unroll
    for (int mt = 0; mt < 6; mt++){
#pragma unroll
        for (int r = 0; r < 4; r++){
            int m2 = mt * 16 + quad * 4 + r;
            int g = m2 / 12, t = m2 - 12 * g;
            float pv = aP[mt][r] + bP, qv = aQ[mt][r] + bQ;
            Ho[g * 864 + t * 72 + o_p] = f2bf(pv / (1.f + __expf(-qv)));
        }
    }
    __syncthreads();
    for (int i = tid; i < 768; i += 256){
        int g = i / 96, r = i % 96, t = r / 8, ch = r % 8;
        *(s16v8*)(out + (size_t)(n0 + g) * 768 + t * 64 + ch * 8) =
            *(const s16v8*)&Ho[g * 864 + t * 72 + ch * 8];
    }
}

// ---------------- epack normalization + zero-pad slots [cnt, UNROLL_SLOTS) ----------------
__global__ void k_norm(const float* __restrict__ deg, const int* __restrict__ cur,
                       int2* __restrict__ ep){
    int i = blockIdx.x * blockDim.x + threadIdx.x;
    int n = i >> 7, slot = i & 127;
    if (n >= N_NODES) return;
    int cnt = cur[n]; if (cnt > BUCKET) cnt = BUCKET;
    if (slot < cnt){
        int2 e = ep[(size_t)n * BUCKET + slot];
        float w = __int_as_float(e.y) * rsqrtf(deg[e.x]) * rsqrtf(deg[n]);
        ep[(size_t)n * BUCKET + slot].y = __float_as_int(w);
    } else if (slot < UNROLL_SLOTS){
        // pad: src=node 0 (row stays L1-hot), weight=0 -> contributes exact 0
        ep[(size_t)n * BUCKET + slot] = make_int2(0, 0);
    }
}

// ---------------- slice-partitioned, edge-parallel GCN gather (pre-normalized weights) ----------------
// slice = blockIdx % 8 (XCD round-robin, per-XCD slice ~1.9 MB L2-resident).
// 8 nodes/block, 32 lanes/node: eg = edge group 0..3, l8 = feature lane 0..7 (12 feats/lane).
// Branchless main path: slots [0,24) processed unconditionally (zero-padded by k_norm).
// Latency-bound kernel (floors: L2 ~7us, TA ~9us, VALU ~3us; observed ~40us at 40% occ):
// __launch_bounds__(256,8) -> 32 waves/CU (VGPR<=64 fits) to double latency hiding.
#define GATHER2(P) { \
    int4 m = *(const int4*)(eb + (P)); \
    const u16* q0 = src + (size_t)(u32)m.x * 768; \
    const u16* q1 = src + (size_t)(u32)m.z * 768; \
    u32v4 a0 = *(const u32v4*)(q0 + off1); u32v2 b0 = *(const u32v2*)(q0 + off2); \
    u32v4 a1 = *(const u32v4*)(q1 + off1); u32v2 b1 = *(const u32v2*)(q1 + off2); \
    f32v2 w0; w0.x = __int_as_float(m.y); w0.y = w0.x; \
    f32v2 w1; w1.x = __int_as_float(m.w); w1.y = w1.x; \
    acc[0] += w0 * up2(a0.x); acc[1] += w0 * up2(a0.y); \
    acc[2] += w0 * up2(a0.z); acc[3] += w0 * up2(a0.w); \
    acc[4] += w0 * up2(b0.x); acc[5] += w0 * up2(b0.y); \
    acc[0] += w1 * up2(a1.x); acc[1] += w1 * up2(a1.y); \
    acc[2] += w1 * up2(a1.z); acc[3] += w1 * up2(a1.w); \
    acc[4] += w1 * up2(b1.x); acc[5] += w1 * up2(b1.y); }

#define GATHER1(P) { \
    int2 e0 = eb[(P)]; \
    const u16* q0 = src + (size_t)(u32)e0.x * 768; \
    u32v4 a0 = *(const u32v4*)(q0 + off1); u32v2 b0 = *(const u32v2*)(q0 + off2); \
    f32v2 w0; w0.x = __int_as_float(e0.y); w0.y = w0.x; \
    acc[0] += w0 * up2(a0.x); acc[1] += w0 * up2(a0.y); \
    acc[2] += w0 * up2(a0.z); acc[3] += w0 * up2(a0.w); \
    acc[4] += w0 * up2(b0.x); acc[5] += w0 * up2(b0.y); }

__launch_bounds__(256, 8)
__global__ void k_gather(const u16* __restrict__ src, const float* __restrict__ deg,
                         const int* __restrict__ cur, const int2* __restrict__ ep,
                         u16* __restrict__ z){
    int slice = blockIdx.x & 7;
    int nb = blockIdx.x >> 3;            // 0..1249
    int tid = threadIdx.x;
    int nl = tid >> 5;                   // node within block (0..7)
    int sub = tid & 31;
    int eg = sub >> 3;                   // edge group 0..3 (owns bucket slots 2g,2g+1 mod 8)
    int l8 = sub & 7;                    // feature-chunk lane 0..7
    int n = nb * 8 + nl;
    int off1 = slice * 96 + l8 * 8;      // 8 feats, 16B-aligned, lane-contiguous
    int off2 = slice * 96 + 64 + l8 * 4; // 4 feats, 8B-aligned, lane-contiguous

    int e = cur[n]; if (e > BUCKET) e = BUCKET;   // issued early; consumed only in rare tail

    f32v2 acc[6];
    if (eg == 0){
        float sw = 1.0f / deg[n];        // self-loop: dis[n]*1*dis[n]
        f32v2 swv; swv.x = sw; swv.y = sw;
        const u16* xr = src + (size_t)n * 768;
        u32v4 sa = *(const u32v4*)(xr + off1);
        u32v2 sb = *(const u32v2*)(xr + off2);
        acc[0] = swv * up2(sa.x); acc[1] = swv * up2(sa.y);
        acc[2] = swv * up2(sa.z); acc[3] = swv * up2(sa.w);
        acc[4] = swv * up2(sb.x); acc[5] = swv * up2(sb.y);
    } else {
#pragma unroll
        for (int k = 0; k < 6; k++) acc[k] = (f32v2)0.f;
    }

    const int2* eb = ep + (size_t)n * BUCKET;
    // branchless main path: slots [0,24), zero-padded beyond cnt
    GATHER2(eg * 2);
    GATHER2(eg * 2 + 8);
    GATHER2(eg * 2 + 16);

    // rare tail (P(deg>24) ~ 2%): pair loop over slots [24, cnt)
    if (e > UNROLL_SLOTS){
        int p = UNROLL_SLOTS + eg * 2;
        for (; p + 1 < e; p += 8) GATHER2(p);
        if (p < e) GATHER1(p);
    }

    // reduce edge-group partials (lanes differ in bits 3,4 — stays within each node's 32 lanes)
    float r[12];
#pragma unroll
    for (int j = 0; j < 6; j++){ r[2 * j] = acc[j].x; r[2 * j + 1] = acc[j].y; }
#pragma unroll
    for (int k = 0; k < 12; k++){
        r[k] += __shfl_xor(r[k], 8, 64);
        r[k] += __shfl_xor(r[k], 16, 64);
    }
    if (eg == 0){
        u16* zo = z + (size_t)n * 768;
        u32v4 ha; ha.x = pk2(r[0], r[1]); ha.y = pk2(r[2], r[3]);
        ha.z = pk2(r[4], r[5]); ha.w = pk2(r[6], r[7]);
        u32v2 hb; hb.x = pk2(r[8], r[9]); hb.y = pk2(r[10], r[11]);
        *(u32v4*)(zo + off1) = ha;
        *(u32v2*)(zo + off2) = hb;
    }
}

// ---------------- fused: stage z -> mix(relu) -> gconv w1 -> (MID: gconv w2 | LAST: final) ----------------
// 8 nodes/block; B-frags loaded per phase with ks-outer loop (24 VGPR live, no spills).
#define XIDX(g, row, c) (((g) * 14 + (row)) * 72 + (c))

template<bool LAST>
__launch_bounds__(256, 4)
__global__ void k_fused(const u16* __restrict__ z,      // [n][t*64+c] bf16 (pre-aggregated)
                        const u16* __restrict__ Wmix, const u16* __restrict__ bmix,
                        const u16* __restrict__ w1, const u16* __restrict__ b1,
                        const u16* __restrict__ w2, const u16* __restrict__ b2,
                        const u16* __restrict__ fw, const u16* __restrict__ fb,
                        u16* __restrict__ outMid, float* __restrict__ outFin){
    __shared__ __attribute__((aligned(16))) u16 bufX[8 * 14 * 72];
    __shared__ __attribute__((aligned(16))) u16 bufY[8 * 14 * 72];
    int tid = threadIdx.x;
    int n0 = blockIdx.x * 8;
    int lane = tid & 63, wave = tid >> 6;
    int col = lane & 15, quad = lane >> 4;
    int o_p = wave * 16 + col, o_q = o_p + 64;

    // zero time-pad rows
    for (int i = tid; i < 8 * 72; i += 256){
        int g = i / 72, c = i % 72;
        bufX[XIDX(g, 0, c)] = 0; bufX[XIDX(g, 13, c)] = 0;
        bufY[XIDX(g, 0, c)] = 0; bufY[XIDX(g, 13, c)] = 0;
    }
    // stage z -> bufX rows 1..12
    for (int i = tid; i < 768; i += 256){
        int g = i / 96, r = i % 96, t = r >> 3, ch = r & 7;
        *(s16v8*)&bufX[XIDX(g, 1 + t, ch * 8)] =
            *(const s16v8*)(z + (size_t)(n0 + g) * 768 + t * 64 + ch * 8);
    }
    __syncthreads();

    // ---- mix MFMA: y = relu(z*W + b), 6 m-tiles ----
    {
        f32v4 accm[6];
#pragma unroll
        for (int mt = 0; mt < 6; mt++) accm[mt] = (f32v4)0.f;
#pragma unroll
        for (int ks = 0; ks < 2; ks++){
            s16v8 Bm = *(const s16v8*)(Wmix + (size_t)o_p * 64 + ks * 32 + quad * 8);
#pragma unroll
            for (int mt = 0; mt < 6; mt++){
                int m = mt * 16 + col;
                int g = m / 12, t = m - 12 * g;
                s16v8 a = *(const s16v8*)&bufX[XIDX(g, 1 + t, ks * 32 + quad * 8)];
                accm[mt] = __builtin_amdgcn_mfma_f32_16x16x32_bf16(a, Bm, accm[mt], 0, 0, 0);
            }
        }
        float bm = bf2f(bmix[o_p]);
#pragma unroll
        for (int mt = 0; mt < 6; mt++){
#pragma unroll
            for (int r = 0; r < 4; r++){
                int m2 = mt * 16 + quad * 4 + r;
                int g = m2 / 12, t = m2 - 12 * g;
                bufY[XIDX(g, 1 + t, o_p)] = f2bf(fmaxf(accm[mt][r] + bm, 0.f));
            }
        }
    }
    __syncthreads();

    // ---- gated conv 1: bufY -> bufX ----
    {
        f32v4 aP[6], aQ[6];
#pragma unroll
        for (int mt = 0; mt < 6; mt++){ aP[mt] = (f32v4)0.f; aQ[mt] = (f32v4)0.f; }
#pragma unroll
        for (int ks = 0; ks < 2; ks++){
            s16v8 Bf[3][2];
#pragma unroll
            for (int pq = 0; pq < 2; pq++){
                int o = pq ? o_q : o_p;
#pragma unroll
                for (int d = 0; d < 3; d++)
                    Bf[d][pq] = *(const s16v8*)(w1 + d * 8192 + o * 64 + ks * 32 + quad * 8);
            }
#pragma unroll
            for (int mt = 0; mt < 6; mt++){
                int m = mt * 16 + col;
                int g = m / 12, t = m - 12 * g;
#pragma unroll
                for (int d = 0; d < 3; d++){
                    s16v8 a = *(const s16v8*)&bufY[XIDX(g, t + d, ks * 32 + quad * 8)];
                    aP[mt] = __builtin_amdgcn_mfma_f32_16x16x32_bf16(a, Bf[d][0], aP[mt], 0, 0, 0);
                    aQ[mt] = __builtin_amdgcn_mfma_f32_16x16x32_bf16(a, Bf[d][1], aQ[mt], 0, 0, 0);
                }
            }
        }
        float bP = bf2f(b1[o_p]), bQ = bf2f(b1[o_q]);
#pragma unroll
        for (int mt = 0; mt < 6; mt++){
#pragma unroll
            for (int r = 0; r < 4; r++){
                int m2 = mt * 16 + quad * 4 + r;
                int g = m2 / 12, t = m2 - 12 * g;
                float pv = aP[mt][r] + bP, qv = aQ[mt][r] + bQ;
                u16 hv = f2bf(pv / (1.f + __expf(-qv)));
                if (LAST) bufX[g * 1008 + o_p * 12 + t] = hv;   // H2[g][c*12+t]
                else      bufX[XIDX(g, 1 + t, o_p)] = hv;
            }
        }
    }
    __syncthreads();

    if (!LAST){
        // ---- gated conv 2: bufX -> bufY -> outMid ----
        f32v4 aP[6], aQ[6];
#pragma unroll
        for (int mt = 0; mt < 6; mt++){ aP[mt] = (f32v4)0.f; aQ[mt] = (f32v4)0.f; }
#pragma unroll
        for (int ks = 0; ks < 2; ks++){
            s16v8 Bf[3][2];
#pragma unroll
            for (int pq = 0; pq < 2; pq++){
                int o = pq ? o_q : o_p;
#pragma unroll
                for (int d = 0; d < 3; d++)
                    Bf[d][pq] = *(const s16v8*)(w2 + d * 8192 + o * 64 + ks * 32 + quad * 8);
            }
#pragma unroll
            for (int mt = 0; mt < 6; mt++){
                int m = mt * 16 + col;
                int g = m / 12, t = m - 12 * g;
#pragma unroll
                for (int d = 0; d < 3; d++){
                    s16v8 a = *(const s16v8*)&bufX[XIDX(g, t + d, ks * 32 + quad * 8)];
                    aP[mt] = __builtin_amdgcn_mfma_f32_16x16x32_bf16(a, Bf[d][0], aP[mt], 0, 0, 0);
                    aQ[mt] = __builtin_amdgcn_mfma_f32_16x16x32_bf16(a, Bf[d][1], aQ[mt], 0, 0, 0);
                }
            }
        }
        float bP = bf2f(b2[o_p]), bQ = bf2f(b2[o_q]);
#pragma unroll
        for (int mt = 0; mt < 6; mt++){
#pragma unroll
            for (int r = 0; r < 4; r++){
                int m2 = mt * 16 + quad * 4 + r;
                int g = m2 / 12, t = m2 - 12 * g;
                float pv = aP[mt][r] + bP, qv = aQ[mt][r] + bQ;
                bufY[XIDX(g, 1 + t, o_p)] = f2bf(pv / (1.f + __expf(-qv)));
            }
        }
        __syncthreads();
        for (int i = tid; i < 768; i += 256){
            int g = i / 96, r = i % 96, t = r / 8, ch = r % 8;
            *(s16v8*)(outMid + (size_t)(n0 + g) * 768 + t * 64 + ch * 8) =
                *(const s16v8*)&bufY[XIDX(g, 1 + t, ch * 8)];
        }
    } else {
        // ---- final: out[g][o] = sum_k H2[g][k]*fw[o][k] + fb[o] (wave 0; 8 nodes in rows 0..7) ----
        if (wave == 0){
            f32v4 accF = {0.f, 0.f, 0.f, 0.f};
            int g8 = col & 7;
#pragma unroll
            for (int ks = 0; ks < 24; ks++){
                s16v8 a = *(const s16v8*)&bufX[g8 * 1008 + ks * 32 + quad * 8];
                s16v8 bfr = {0, 0, 0, 0, 0, 0, 0, 0};
                if (col < 12)
                    bfr = *(const s16v8*)(fw + (size_t)col * 768 + ks * 32 + quad * 8);
                accF = __builtin_amdgcn_mfma_f32_16x16x32_bf16(a, bfr, accF, 0, 0, 0);
            }
            if (col < 12 && quad < 2){
                float bb = bf2f(fb[col]);
#pragma unroll
                for (int r = 0; r < 4; r++){
                    int g = quad * 4 + r;
                    outFin[(size_t)(n0 + g) * 12 + col] = accF[r] + bb;
                }
            }
        }
    }
}

// ---------------- launch ----------------
static inline size_t align256(size_t x){ return (x + 255) & ~(size_t)255; }

extern "C" void kernel_launch(void* const* d_in, const int* in_sizes, int n_in,
                              void* d_out, int out_size, void* d_ws, size_t ws_size,
                              hipStream_t stream){
    const float* x  = (const float*)d_in[0];
    const int* ei   = (const int*)d_in[1];
    const float* ew = (const float*)d_in[2];

    char* w = (char*)d_ws;
    u16* bufA    = (u16*)w;  w += align256((size_t)N_NODES * 768 * sizeof(u16));
    u16* bufB    = (u16*)w;  w += align256((size_t)N_NODES * 768 * sizeof(u16));
    u16* zA      = (u16*)w;  w += align256((size_t)N_NODES * 768 * sizeof(u16));
    u16* zB      = (u16*)w;  w += align256((size_t)N_NODES * 768 * sizeof(u16));
    float* deg   = (float*)w; w += align256(N_NODES * sizeof(float));
    int* cur     = (int*)w;   w += align256(N_NODES * sizeof(int));
    int2* epack  = (int2*)w;  w += align256((size_t)N_NODES * BUCKET * sizeof(int2));
    u16* cvt     = (u16*)w;   w += align256(104076 * sizeof(u16));

    u16* tc1a_w = cvt + 0;        // [d][128][32]
    u16* tc1a_b = cvt + 12288;
    u16* gc1_w  = cvt + 12416;
    u16* gc1_b  = cvt + 16512;
    u16* tc1b_w = cvt + 16576;    // [d][128][64]
    u16* tc1b_b = cvt + 41152;
    u16* tc2a_w = cvt + 41280;    // [d][128][64]
    u16* tc2a_b = cvt + 65856;
    u16* gc2_w  = cvt + 65984;
    u16* gc2_b  = cvt + 70080;
    u16* tc2b_w = cvt + 70144;    // [d][128][64]
    u16* tc2b_b = cvt + 94720;
    u16* fin_w  = cvt + 94848;
    u16* fin_b  = cvt + 104064;

    SmallPtrs ps;
    ps.p[0]  = d_in[3];  ps.p[1]  = d_in[4];
    ps.p[2]  = d_in[5];  ps.p[3]  = d_in[6];
    ps.p[4]  = d_in[7];  ps.p[5]  = d_in[8];
    ps.p[6]  = d_in[9];  ps.p[7]  = d_in[10];
    ps.p[8]  = d_in[11]; ps.p[9]  = d_in[12];
    ps.p[10] = d_in[13]; ps.p[11] = d_in[14];
    ps.p[12] = d_in[15]; ps.p[13] = d_in[16];

    k_convert_init<<<(104076 + 255) / 256, 256, 0, stream>>>(ps, cvt, deg, cur);
    k_gconv_count<<<1250 + 625, 256, 0, stream>>>(x, tc1a_w, tc1a_b, bufA, ei, ew, deg, cur, epack);
    k_norm<<<(N_NODES * BUCKET) / 256, 256, 0, stream>>>(deg, cur, epack);

    k_gather<<<1250 * 8, 256, 0, stream>>>(bufA, deg, cur, epack, zA);
    k_fused<false><<<1250, 256, 0, stream>>>(zA, gc1_w, gc1_b, tc1b_w, tc1b_b,
                                             tc2a_w, tc2a_b, nullptr, nullptr,
                                             bufB, nullptr);
    k_gather<<<1250 * 8, 256, 0, stream>>>(bufB, deg, cur, epack, zB);
    k_fused<true><<<1250, 256, 0, stream>>>(zB, gc2_w, gc2_b, tc2b_w, tc2b_b,
                                            nullptr, nullptr, fin_w, fin_b,
                                            nullptr, (float*)d_out);
}

// Round 4
// 225.420 us; speedup vs baseline: 1.0852x; 1.0058x over previous
//
#include <hip/hip_runtime.h>
#include <hip/hip_bf16.h>
#include <stdint.h>

#define N_NODES 10000
#define N_EDGES 160000
#define BUCKET 128
#define UNROLL_SLOTS 24   // slots [0,24) processed branchlessly; k_norm zero-pads [cnt,24)

typedef unsigned short u16;
typedef unsigned int u32;
typedef short s16v8 __attribute__((ext_vector_type(8)));
typedef float f32v4 __attribute__((ext_vector_type(4)));
typedef float f32v2 __attribute__((ext_vector_type(2)));
typedef unsigned int u32v4 __attribute__((ext_vector_type(4)));
typedef unsigned int u32v2 __attribute__((ext_vector_type(2)));

__device__ __forceinline__ float bf2f(u16 v){ return __uint_as_float(((u32)v) << 16); }
__device__ __forceinline__ u16 f2bf(float f){
    u32 u = __float_as_uint(f);
    u32 r = (u + 0x7fffu + ((u >> 16) & 1u)) >> 16;
    return (u16)r;
}
// unpack u32 holding 2 bf16 -> float2 (lo, hi)
__device__ __forceinline__ f32v2 up2(u32 v){
    f32v2 r;
    r.x = __uint_as_float(v << 16);
    r.y = __uint_as_float(v & 0xffff0000u);
    return r;
}
__device__ __forceinline__ u32 pk2(float lo, float hi){
    return (u32)f2bf(lo) | ((u32)f2bf(hi) << 16);
}

// ---------------- weights fp32->bf16 (+tconv transpose to [d][o][c]) + graph init ----------------
struct SmallPtrs { const void* p[14]; };

__device__ __constant__ const int g_seg_off[15] = {
    0, 12288, 12416, 16512, 16576, 41152, 41280,
    65856, 65984, 70080, 70144, 94720, 94848, 104064, 104076
};
// 0=straight, 1=tconv CIN=32 transpose, 2=tconv CIN=64 transpose
__device__ __constant__ const int g_seg_kind[14] = {
    1, 0, 0, 0, 2, 0, 2, 0, 0, 0, 2, 0, 0, 0
};

__global__ void k_convert_init(SmallPtrs ps, u16* __restrict__ dst,
                               float* deg, int* cur){
    int i = blockIdx.x * blockDim.x + threadIdx.x;
    if (i < 104076){
        int seg = 0, base = 0;
#pragma unroll
        for (int s = 0; s < 14; s++){
            if (i >= g_seg_off[s]){ seg = s; base = g_seg_off[s]; }
        }
        int li = i - base;
        float v = ((const float*)ps.p[seg])[li];
        int kind = g_seg_kind[seg];
        int dsto = li;
        if (kind){
            int CIN = (kind == 1) ? 32 : 64;
            int o = li / (3 * CIN);
            int rem = li - o * (3 * CIN);
            int c = rem / 3, d = rem - c * 3;
            dsto = d * 128 * CIN + o * CIN + c;     // [d][o][c]
        }
        dst[base + dsto] = f2bf(v);
    }
    if (i < N_NODES){ deg[i] = 1.0f; cur[i] = 0; }
}

// ---------------- merged: gconv32 (blocks 0..1249) || deg + bucket-scatter (1250..1874) ----------------
// LDS union: xT [8][14][40] (8960 B) overlaid with Ho [8][12][72] (13824 B) -> 13.8 KB total.
__launch_bounds__(256, 4)
__global__ void k_gconv_count(const float* __restrict__ xin, const u16* __restrict__ wg,
                              const u16* __restrict__ bg, u16* __restrict__ out,
                              const int* __restrict__ ei, const float* __restrict__ ew,
                              float* deg, int* cur, int2* __restrict__ epack){
    if (blockIdx.x >= 1250){
        int e = (blockIdx.x - 1250) * 256 + threadIdx.x;
        if (e < N_EDGES){
            int s = ei[e];
            int d = ei[N_EDGES + e];
            float wv = ew[e];
            atomicAdd(&deg[d], wv);
            int p = atomicAdd(&cur[d], 1);
            if (p < BUCKET) epack[d * BUCKET + p] = make_int2(s, __float_as_int(wv));
        }
        return;
    }
    __shared__ __attribute__((aligned(16))) u16 shbuf[6912];   // 13824 B union
    u16* xT = shbuf;    // [g][row][c] = g*560 + row*40 + c  (rows 0..13, c 0..39)
    u16* Ho = shbuf;    // [g][t][o]   = g*864 + t*72 + o    (after MFMA, overwrites xT)
    int tid = threadIdx.x;
    int n0 = blockIdx.x * 8;

    int lane = tid & 63, wave = tid >> 6;
    int col = lane & 15, quad = lane >> 4;
    int o_p = wave * 16 + col, o_q = o_p + 64;

    s16v8 Bf[3][2];
#pragma unroll
    for (int pq = 0; pq < 2; pq++){
        int o = pq ? o_q : o_p;
#pragma unroll
        for (int d = 0; d < 3; d++)
            Bf[d][pq] = *(const s16v8*)(wg + d * 4096 + o * 32 + quad * 8);
    }

    for (int i = tid; i < 8 * 40; i += 256){
        int g = i / 40, c = i % 40;
        xT[g * 560 + 0 * 40 + c] = 0; xT[g * 560 + 13 * 40 + c] = 0;
    }
    {
        int g = tid >> 5, c = tid & 31;
        const float4* p = (const float4*)(xin + ((size_t)(n0 + g) * 32 + c) * 12);
        float4 v0 = p[0], v1 = p[1], v2 = p[2];
        u16* xb = xT + g * 560 + c;
        xb[1 * 40] = f2bf(v0.x);  xb[2 * 40] = f2bf(v0.y);
        xb[3 * 40] = f2bf(v0.z);  xb[4 * 40] = f2bf(v0.w);
        xb[5 * 40] = f2bf(v1.x);  xb[6 * 40] = f2bf(v1.y);
        xb[7 * 40] = f2bf(v1.z);  xb[8 * 40] = f2bf(v1.w);
        xb[9 * 40] = f2bf(v2.x);  xb[10 * 40] = f2bf(v2.y);
        xb[11 * 40] = f2bf(v2.z); xb[12 * 40] = f2bf(v2.w);
    }
    __syncthreads();

    f32v4 aP[6], aQ[6];
#pragma unroll
    for (int mt = 0; mt < 6; mt++){ aP[mt] = (f32v4)0.f; aQ[mt] = (f32v4)0.f; }
#pragma unroll
    for (int mt = 0; mt < 6; mt++){
        int m = mt * 16 + col;
        int g = m / 12, t = m - 12 * g;
#pragma unroll
        for (int d = 0; d < 3; d++){
            s16v8 a = *(const s16v8*)&xT[g * 560 + (t + d) * 40 + quad * 8];
            aP[mt] = __builtin_amdgcn_mfma_f32_16x16x32_bf16(a, Bf[d][0], aP[mt], 0, 0, 0);
            aQ[mt] = __builtin_amdgcn_mfma_f32_16x16x32_bf16(a, Bf[d][1], aQ[mt], 0, 0, 0);
        }
    }
    __syncthreads();   // all xT reads done before Ho overwrites the union buffer
    float bP = bf2f(bg[o_p]), bQ = bf2f(bg[o_q]);
#pragma unroll
    for (int mt = 0; mt < 6; mt++){
#pragma unroll
        for (int r = 0; r < 4; r++){
            int m2 = mt * 16 + quad * 4 + r;
            int g = m2 / 12, t = m2 - 12 * g;
            float pv = aP[mt][r] + bP, qv = aQ[mt][r] + bQ;
            Ho[g * 864 + t * 72 + o_p] = f2bf(pv / (1.f + __expf(-qv)));
        }
    }
    __syncthreads();
    for (int i = tid; i < 768; i += 256){
        int g = i / 96, r = i % 96, t = r / 8, ch = r % 8;
        *(s16v8*)(out + (size_t)(n0 + g) * 768 + t * 64 + ch * 8) =
            *(const s16v8*)&Ho[g * 864 + t * 72 + ch * 8];
    }
}

// ---------------- epack normalization + zero-pad slots [cnt, UNROLL_SLOTS) ----------------
__global__ void k_norm(const float* __restrict__ deg, const int* __restrict__ cur,
                       int2* __restrict__ ep){
    int i = blockIdx.x * blockDim.x + threadIdx.x;
    int n = i >> 7, slot = i & 127;
    if (n >= N_NODES) return;
    int cnt = cur[n]; if (cnt > BUCKET) cnt = BUCKET;
    if (slot < cnt){
        int2 e = ep[(size_t)n * BUCKET + slot];
        float w = __int_as_float(e.y) * rsqrtf(deg[e.x]) * rsqrtf(deg[n]);
        ep[(size_t)n * BUCKET + slot].y = __float_as_int(w);
    } else if (slot < UNROLL_SLOTS){
        // pad: src=node 0 (row stays cache-hot), weight=0 -> contributes exact 0
        ep[(size_t)n * BUCKET + slot] = make_int2(0, 0);
    }
}

// ---------------- merged gather + fused MFMA pipeline ----------------
// Per block: 8 nodes. Gather phase: 32 lanes/node, lane owns feats {l*8..+7, 256+l*8..+7,
// 512+l*8..+7} (3 x 512B lane-contiguous loads per edge row = 24 lines/edge, optimal).
// Serial accumulation over 24 branchless zero-padded slots -> results written straight to
// LDS bufX (no z round-trip, no shfl). Gather VMEM of some blocks overlaps MFMA of others.
#define XIDX(g, row, c) (((g) * 14 + (row)) * 72 + (c))

#define GFMA(W, A0, A1, A2) { \
    acc[0]  += (W) * up2((A0).x); acc[1]  += (W) * up2((A0).y); \
    acc[2]  += (W) * up2((A0).z); acc[3]  += (W) * up2((A0).w); \
    acc[4]  += (W) * up2((A1).x); acc[5]  += (W) * up2((A1).y); \
    acc[6]  += (W) * up2((A1).z); acc[7]  += (W) * up2((A1).w); \
    acc[8]  += (W) * up2((A2).x); acc[9]  += (W) * up2((A2).y); \
    acc[10] += (W) * up2((A2).z); acc[11] += (W) * up2((A2).w); }

#define GPAIR(P) { \
    int4 m = *(const int4*)(eb + (P)); \
    const u16* q0 = src + (size_t)(u32)m.x * 768 + fo; \
    const u16* q1 = src + (size_t)(u32)m.z * 768 + fo; \
    u32v4 a0 = *(const u32v4*)(q0); \
    u32v4 a1 = *(const u32v4*)(q0 + 256); \
    u32v4 a2 = *(const u32v4*)(q0 + 512); \
    u32v4 c0 = *(const u32v4*)(q1); \
    u32v4 c1 = *(const u32v4*)(q1 + 256); \
    u32v4 c2 = *(const u32v4*)(q1 + 512); \
    f32v2 w0; w0.x = __int_as_float(m.y); w0.y = w0.x; \
    f32v2 w1; w1.x = __int_as_float(m.w); w1.y = w1.x; \
    GFMA(w0, a0, a1, a2); \
    GFMA(w1, c0, c1, c2); }

#define GSINGLE(P) { \
    int2 e0 = eb[(P)]; \
    const u16* q0 = src + (size_t)(u32)e0.x * 768 + fo; \
    u32v4 a0 = *(const u32v4*)(q0); \
    u32v4 a1 = *(const u32v4*)(q0 + 256); \
    u32v4 a2 = *(const u32v4*)(q0 + 512); \
    f32v2 w0; w0.x = __int_as_float(e0.y); w0.y = w0.x; \
    GFMA(w0, a0, a1, a2); }

template<bool LAST>
__launch_bounds__(256, 4)
__global__ void k_gfused(const u16* __restrict__ src,   // bufA or bufB: [n][768] bf16 rows
                         const float* __restrict__ deg, const int* __restrict__ cur,
                         const int2* __restrict__ ep,
                         const u16* __restrict__ Wmix, const u16* __restrict__ bmix,
                         const u16* __restrict__ w1, const u16* __restrict__ b1,
                         const u16* __restrict__ w2, const u16* __restrict__ b2,
                         const u16* __restrict__ fw, const u16* __restrict__ fb,
                         u16* __restrict__ outMid, float* __restrict__ outFin){
    __shared__ __attribute__((aligned(16))) u16 bufX[8 * 14 * 72];
    __shared__ __attribute__((aligned(16))) u16 bufY[8 * 14 * 72];
    int tid = threadIdx.x;
    int n0 = blockIdx.x * 8;
    int lane = tid & 63, wave = tid >> 6;
    int col = lane & 15, quad = lane >> 4;
    int o_p = wave * 16 + col, o_q = o_p + 64;

    // zero time-pad rows
    for (int i = tid; i < 8 * 72; i += 256){
        int g = i / 72, c = i % 72;
        bufX[XIDX(g, 0, c)] = 0; bufX[XIDX(g, 13, c)] = 0;
        bufY[XIDX(g, 0, c)] = 0; bufY[XIDX(g, 13, c)] = 0;
    }

    // ---- gather phase: 32 lanes per node ----
    {
        int nl = tid >> 5;               // node within block 0..7
        int l  = tid & 31;               // feature lane
        int n  = n0 + nl;
        int fo = l * 8;                  // u16 offset of this lane's first 8-feat group
        int e = cur[n]; if (e > BUCKET) e = BUCKET;   // early; used only in rare tail

        f32v2 acc[12];
        {
            float sw = 1.0f / deg[n];    // self-loop: dis[n]*1*dis[n]
            f32v2 swv; swv.x = sw; swv.y = sw;
            const u16* q = src + (size_t)n * 768 + fo;
            u32v4 s0 = *(const u32v4*)(q);
            u32v4 s1 = *(const u32v4*)(q + 256);
            u32v4 s2 = *(const u32v4*)(q + 512);
            acc[0]  = swv * up2(s0.x); acc[1]  = swv * up2(s0.y);
            acc[2]  = swv * up2(s0.z); acc[3]  = swv * up2(s0.w);
            acc[4]  = swv * up2(s1.x); acc[5]  = swv * up2(s1.y);
            acc[6]  = swv * up2(s1.z); acc[7]  = swv * up2(s1.w);
            acc[8]  = swv * up2(s2.x); acc[9]  = swv * up2(s2.y);
            acc[10] = swv * up2(s2.z); acc[11] = swv * up2(s2.w);
        }

        const int2* eb = ep + (size_t)n * BUCKET;
        // branchless: slots [0,24) zero-padded by k_norm
        GPAIR(0);  GPAIR(2);  GPAIR(4);  GPAIR(6);
        GPAIR(8);  GPAIR(10); GPAIR(12); GPAIR(14);
        GPAIR(16); GPAIR(18); GPAIR(20); GPAIR(22);

        // rare tail (P(deg>24) ~ 2%)
        if (e > UNROLL_SLOTS){
            int p = UNROLL_SLOTS;
            for (; p + 1 < e; p += 2) GPAIR(p);
            if (p < e) GSINGLE(p);
        }

        // write results straight into bufX rows 1..12 (feats gi*256 + l*8 .. +7)
#pragma unroll
        for (int gi = 0; gi < 3; gi++){
            int f0 = gi * 256 + fo;
            int t = f0 >> 6, c = f0 & 63;
            u32v4 hv;
            hv.x = pk2(acc[4 * gi + 0].x, acc[4 * gi + 0].y);
            hv.y = pk2(acc[4 * gi + 1].x, acc[4 * gi + 1].y);
            hv.z = pk2(acc[4 * gi + 2].x, acc[4 * gi + 2].y);
            hv.w = pk2(acc[4 * gi + 3].x, acc[4 * gi + 3].y);
            *(u32v4*)&bufX[XIDX(nl, 1 + t, c)] = hv;
        }
    }
    __syncthreads();

    // ---- mix MFMA: y = relu(z*W + b), 6 m-tiles ----
    {
        f32v4 accm[6];
#pragma unroll
        for (int mt = 0; mt < 6; mt++) accm[mt] = (f32v4)0.f;
#pragma unroll
        for (int ks = 0; ks < 2; ks++){
            s16v8 Bm = *(const s16v8*)(Wmix + (size_t)o_p * 64 + ks * 32 + quad * 8);
#pragma unroll
            for (int mt = 0; mt < 6; mt++){
                int m = mt * 16 + col;
                int g = m / 12, t = m - 12 * g;
                s16v8 a = *(const s16v8*)&bufX[XIDX(g, 1 + t, ks * 32 + quad * 8)];
                accm[mt] = __builtin_amdgcn_mfma_f32_16x16x32_bf16(a, Bm, accm[mt], 0, 0, 0);
            }
        }
        float bm = bf2f(bmix[o_p]);
#pragma unroll
        for (int mt = 0; mt < 6; mt++){
#pragma unroll
            for (int r = 0; r < 4; r++){
                int m2 = mt * 16 + quad * 4 + r;
                int g = m2 / 12, t = m2 - 12 * g;
                bufY[XIDX(g, 1 + t, o_p)] = f2bf(fmaxf(accm[mt][r] + bm, 0.f));
            }
        }
    }
    __syncthreads();

    // ---- gated conv 1: bufY -> bufX ----
    {
        f32v4 aP[6], aQ[6];
#pragma unroll
        for (int mt = 0; mt < 6; mt++){ aP[mt] = (f32v4)0.f; aQ[mt] = (f32v4)0.f; }
#pragma unroll
        for (int ks = 0; ks < 2; ks++){
            s16v8 Bf[3][2];
#pragma unroll
            for (int pq = 0; pq < 2; pq++){
                int o = pq ? o_q : o_p;
#pragma unroll
                for (int d = 0; d < 3; d++)
                    Bf[d][pq] = *(const s16v8*)(w1 + d * 8192 + o * 64 + ks * 32 + quad * 8);
            }
#pragma unroll
            for (int mt = 0; mt < 6; mt++){
                int m = mt * 16 + col;
                int g = m / 12, t = m - 12 * g;
#pragma unroll
                for (int d = 0; d < 3; d++){
                    s16v8 a = *(const s16v8*)&bufY[XIDX(g, t + d, ks * 32 + quad * 8)];
                    aP[mt] = __builtin_amdgcn_mfma_f32_16x16x32_bf16(a, Bf[d][0], aP[mt], 0, 0, 0);
                    aQ[mt] = __builtin_amdgcn_mfma_f32_16x16x32_bf16(a, Bf[d][1], aQ[mt], 0, 0, 0);
                }
            }
        }
        float bP = bf2f(b1[o_p]), bQ = bf2f(b1[o_q]);
#pragma unroll
        for (int mt = 0; mt < 6; mt++){
#pragma unroll
            for (int r = 0; r < 4; r++){
                int m2 = mt * 16 + quad * 4 + r;
                int g = m2 / 12, t = m2 - 12 * g;
                float pv = aP[mt][r] + bP, qv = aQ[mt][r] + bQ;
                u16 hv = f2bf(pv / (1.f + __expf(-qv)));
                if (LAST) bufX[g * 1008 + o_p * 12 + t] = hv;   // H2[g][c*12+t]
                else      bufX[XIDX(g, 1 + t, o_p)] = hv;
            }
        }
    }
    __syncthreads();

    if (!LAST){
        // ---- gated conv 2: bufX -> bufY -> outMid ----
        f32v4 aP[6], aQ[6];
#pragma unroll
        for (int mt = 0; mt < 6; mt++){ aP[mt] = (f32v4)0.f; aQ[mt] = (f32v4)0.f; }
#pragma unroll
        for (int ks = 0; ks < 2; ks++){
            s16v8 Bf[3][2];
#pragma unroll
            for (int pq = 0; pq < 2; pq++){
                int o = pq ? o_q : o_p;
#pragma unroll
                for (int d = 0; d < 3; d++)
                    Bf[d][pq] = *(const s16v8*)(w2 + d * 8192 + o * 64 + ks * 32 + quad * 8);
            }
#pragma unroll
            for (int mt = 0; mt < 6; mt++){
                int m = mt * 16 + col;
                int g = m / 12, t = m - 12 * g;
#pragma unroll
                for (int d = 0; d < 3; d++){
                    s16v8 a = *(const s16v8*)&bufX[XIDX(g, t + d, ks * 32 + quad * 8)];
                    aP[mt] = __builtin_amdgcn_mfma_f32_16x16x32_bf16(a, Bf[d][0], aP[mt], 0, 0, 0);
                    aQ[mt] = __builtin_amdgcn_mfma_f32_16x16x32_bf16(a, Bf[d][1], aQ[mt], 0, 0, 0);
                }
            }
        }
        float bP = bf2f(b2[o_p]), bQ = bf2f(b2[o_q]);
#pragma unroll
        for (int mt = 0; mt < 6; mt++){
#pragma unroll
            for (int r = 0; r < 4; r++){
                int m2 = mt * 16 + quad * 4 + r;
                int g = m2 / 12, t = m2 - 12 * g;
                float pv = aP[mt][r] + bP, qv = aQ[mt][r] + bQ;
                bufY[XIDX(g, 1 + t, o_p)] = f2bf(pv / (1.f + __expf(-qv)));
            }
        }
        __syncthreads();
        for (int i = tid; i < 768; i += 256){
            int g = i / 96, r = i % 96, t = r / 8, ch = r % 8;
            *(s16v8*)(outMid + (size_t)(n0 + g) * 768 + t * 64 + ch * 8) =
                *(const s16v8*)&bufY[XIDX(g, 1 + t, ch * 8)];
        }
    } else {
        // ---- final: out[g][o] = sum_k H2[g][k]*fw[o][k] + fb[o] (wave 0; 8 nodes in rows 0..7) ----
        if (wave == 0){
            f32v4 accF = {0.f, 0.f, 0.f, 0.f};
            int g8 = col & 7;
#pragma unroll
            for (int ks = 0; ks < 24; ks++){
                s16v8 a = *(const s16v8*)&bufX[g8 * 1008 + ks * 32 + quad * 8];
                s16v8 bfr = {0, 0, 0, 0, 0, 0, 0, 0};
                if (col < 12)
                    bfr = *(const s16v8*)(fw + (size_t)col * 768 + ks * 32 + quad * 8);
                accF = __builtin_amdgcn_mfma_f32_16x16x32_bf16(a, bfr, accF, 0, 0, 0);
            }
            if (col < 12 && quad < 2){
                float bb = bf2f(fb[col]);
#pragma unroll
                for (int r = 0; r < 4; r++){
                    int g = quad * 4 + r;
                    outFin[(size_t)(n0 + g) * 12 + col] = accF[r] + bb;
                }
            }
        }
    }
}

// ---------------- launch ----------------
static inline size_t align256(size_t x){ return (x + 255) & ~(size_t)255; }

extern "C" void kernel_launch(void* const* d_in, const int* in_sizes, int n_in,
                              void* d_out, int out_size, void* d_ws, size_t ws_size,
                              hipStream_t stream){
    const float* x  = (const float*)d_in[0];
    const int* ei   = (const int*)d_in[1];
    const float* ew = (const float*)d_in[2];

    char* w = (char*)d_ws;
    u16* bufA    = (u16*)w;  w += align256((size_t)N_NODES * 768 * sizeof(u16));
    u16* bufB    = (u16*)w;  w += align256((size_t)N_NODES * 768 * sizeof(u16));
    float* deg   = (float*)w; w += align256(N_NODES * sizeof(float));
    int* cur     = (int*)w;   w += align256(N_NODES * sizeof(int));
    int2* epack  = (int2*)w;  w += align256((size_t)N_NODES * BUCKET * sizeof(int2));
    u16* cvt     = (u16*)w;   w += align256(104076 * sizeof(u16));

    u16* tc1a_w = cvt + 0;        // [d][128][32]
    u16* tc1a_b = cvt + 12288;
    u16* gc1_w  = cvt + 12416;
    u16* gc1_b  = cvt + 16512;
    u16* tc1b_w = cvt + 16576;    // [d][128][64]
    u16* tc1b_b = cvt + 41152;
    u16* tc2a_w = cvt + 41280;    // [d][128][64]
    u16* tc2a_b = cvt + 65856;
    u16* gc2_w  = cvt + 65984;
    u16* gc2_b  = cvt + 70080;
    u16* tc2b_w = cvt + 70144;    // [d][128][64]
    u16* tc2b_b = cvt + 94720;
    u16* fin_w  = cvt + 94848;
    u16* fin_b  = cvt + 104064;

    SmallPtrs ps;
    ps.p[0]  = d_in[3];  ps.p[1]  = d_in[4];
    ps.p[2]  = d_in[5];  ps.p[3]  = d_in[6];
    ps.p[4]  = d_in[7];  ps.p[5]  = d_in[8];
    ps.p[6]  = d_in[9];  ps.p[7]  = d_in[10];
    ps.p[8]  = d_in[11]; ps.p[9]  = d_in[12];
    ps.p[10] = d_in[13]; ps.p[11] = d_in[14];
    ps.p[12] = d_in[15]; ps.p[13] = d_in[16];

    k_convert_init<<<(104076 + 255) / 256, 256, 0, stream>>>(ps, cvt, deg, cur);
    k_gconv_count<<<1250 + 625, 256, 0, stream>>>(x, tc1a_w, tc1a_b, bufA, ei, ew, deg, cur, epack);
    k_norm<<<(N_NODES * BUCKET) / 256, 256, 0, stream>>>(deg, cur, epack);

    k_gfused<false><<<1250, 256, 0, stream>>>(bufA, deg, cur, epack,
                                              gc1_w, gc1_b, tc1b_w, tc1b_b,
                                              tc2a_w, tc2a_b, nullptr, nullptr,
                                              bufB, nullptr);
    k_gfused<true><<<1250, 256, 0, stream>>>(bufB, deg, cur, epack,
                                             gc2_w, gc2_b, tc2b_w, tc2b_b,
                                             nullptr, nullptr, fin_w, fin_b,
                                             nullptr, (float*)d_out);
}